// Round 18
// baseline (404.693 us; speedup 1.0000x reference)
//
#include <hip/hip_runtime.h>
#include <hip/hip_bf16.h>
#include <math.h>

// Problem constants (compile-time)
#define DIMC   256
#define HH     48
#define WW     64
#define MROWS  (HH*WW)     // 3072
#define NHEADS 8
#define HD     32
#define KTAP   13
#define NTAPS  (KTAP*KTAP) // 169
#define DIL    3
#define NB     6           // KTAP/2
#define EPSLN  1e-5f
#define QSCALE 0.17677669529663687f  // 32^-0.5

typedef __attribute__((ext_vector_type(8))) short bf16x8;
typedef __attribute__((ext_vector_type(4))) float f32x4;
typedef _Float16 __f16;
typedef __f16 f16x2 __attribute__((ext_vector_type(2)));

__device__ __forceinline__ f16x2 pkh(float a, float b) {
    auto r = __builtin_amdgcn_cvt_pkrtz(a, b);
    return __builtin_bit_cast(f16x2, r);
}
__device__ __forceinline__ f16x2 bch(unsigned u) {
    return __builtin_bit_cast(f16x2, u);
}

// ---------------- window/bias start helpers (static arithmetic) -------------
__device__ __forceinline__ int win_start(int i, int L) {
    int imodd = i % DIL;
    if (i - NB * DIL < 0) return imodd;
    if (i + NB * DIL >= L) {
        int a = (L / DIL) * DIL;
        int b = L - a;
        if (imodd < b) return L - b + imodd - 2 * NB * DIL;
        return a + imodd - KTAP * DIL;
    }
    return i - NB * DIL;
}
__device__ __forceinline__ int pb_start(int i, int L) {
    if (i - NB * DIL < 0) return KTAP - 1 - i / DIL;
    if (i + NB * DIL >= L) return (L - 1 - i) / DIL;
    return NB;
}

// ---------------- fp32 -> bf16 conversion, all 4 weight buffers in 1 launch --
__global__ __launch_bounds__(256) void cvt_all_kernel(const float* __restrict__ w0,
                                                      const float* __restrict__ w1,
                                                      const float* __restrict__ w2,
                                                      const float* __restrict__ w3,
                                                      __hip_bfloat16* __restrict__ o0,
                                                      __hip_bfloat16* __restrict__ o1,
                                                      __hip_bfloat16* __restrict__ o2,
                                                      __hip_bfloat16* __restrict__ o3) {
    int i = blockIdx.x * 256 + threadIdx.x;
    const float* in;
    __hip_bfloat16* out;
    int off;
    if (i < 294912)      { in = w0; out = o0; off = i; }
    else if (i < 393216) { in = w1; out = o1; off = i - 294912; }
    else if (i < 786432) { in = w2; out = o2; off = i - 393216; }
    else                 { in = w3; out = o3; off = i - 786432; }
    float4 v = ((const float4*)in)[off];
    union { __hip_bfloat16 h[4]; ushort4 u; } p;
    p.h[0] = __float2bfloat16(v.x);
    p.h[1] = __float2bfloat16(v.y);
    p.h[2] = __float2bfloat16(v.z);
    p.h[3] = __float2bfloat16(v.w);
    ((ushort4*)out)[off] = p.u;
}

// ---------------- input transpose: x (C, H*W) -> t (H*W, C) -----------------
__global__ void transpose_in_kernel(const float* __restrict__ x, float* __restrict__ t) {
    int m = blockIdx.x;
    int c = threadIdx.x;
    t[m * DIMC + c] = x[c * MROWS + m];
}

// ---------------- layernorm; OutT float or bf16; optional transposed store ---
template <typename OutT, int TRANS>
__global__ __launch_bounds__(256) void ln_kernel(const float* __restrict__ in,
                                                 const float* __restrict__ w,
                                                 const float* __restrict__ b,
                                                 OutT* __restrict__ out) {
    __shared__ float s1[4], s2[4];
    int m = blockIdx.x;
    int c = threadIdx.x;
    float v = in[m * DIMC + c];
    float a = v, q = v * v;
    #pragma unroll
    for (int o = 32; o > 0; o >>= 1) {
        a += __shfl_xor(a, o);
        q += __shfl_xor(q, o);
    }
    if ((threadIdx.x & 63) == 0) { s1[threadIdx.x >> 6] = a; s2[threadIdx.x >> 6] = q; }
    __syncthreads();
    float mean = (s1[0] + s1[1] + s1[2] + s1[3]) * (1.0f / DIMC);
    float var  = (s2[0] + s2[1] + s2[2] + s2[3]) * (1.0f / DIMC) - mean * mean;
    float r = (v - mean) * rsqrtf(var + EPSLN) * w[c] + b[c];
    if (TRANS) {
        out[c * MROWS + m] = (OutT)r;
    } else {
        if constexpr (sizeof(OutT) == 2) out[m * DIMC + c] = __float2bfloat16(r);
        else                             out[m * DIMC + c] = r;
    }
}

// ---------------- bf16 MFMA GEMM: C = A * W^T + bias -------------------------
// 18.4 KB LDS, 1024 threads / 16 waves per 64x64 tile (wave = 16x16 sub-tile):
// proj/fc2 go to 4 waves/SIMD (R16 proved waves/SIMD is the binding
// constraint). Register double-buffer (R12-proven).
#define LDP 72
template <int EPI, typename OutT>
__global__ __launch_bounds__(1024) void gemm_mfma_kernel(const __hip_bfloat16* __restrict__ A,
                                                         const __hip_bfloat16* __restrict__ Wt,
                                                         const float* __restrict__ bias,
                                                         const float* __restrict__ res,
                                                         OutT* __restrict__ C,
                                                         int M, int N, int K) {
    __shared__ __hip_bfloat16 As[64][LDP];
    __shared__ __hip_bfloat16 Ws[64][LDP];
    int tid = threadIdx.x;
    int bm = blockIdx.y * 64, bn = blockIdx.x * 64;
    int lane = tid & 63, wid = tid >> 6;      // 16 waves
    int wr = wid & 3, wc = wid >> 2;          // wave: rows wr*16, cols wc*16
    int fr = lane & 15, fq = lane >> 4;
    int sr = tid >> 4, sc = (tid & 15) << 2;  // staging row/col (1024 = 64x16)
    f32x4 acc = {};

    // prologue: load tile 0 into registers (1 uint2 per thread each)
    uint2 ra, rw;
    ra = *(const uint2*)&A[(size_t)(bm + sr) * K + sc];
    rw = *(const uint2*)&Wt[(size_t)(bn + sr) * K + sc];

    for (int k0 = 0; k0 < K; k0 += 64) {
        *(uint2*)&As[sr][sc] = ra;
        *(uint2*)&Ws[sr][sc] = rw;
        __syncthreads();
        if (k0 + 64 < K) {
            ra = *(const uint2*)&A[(size_t)(bm + sr) * K + k0 + 64 + sc];
            rw = *(const uint2*)&Wt[(size_t)(bn + sr) * K + k0 + 64 + sc];
        }
        #pragma unroll
        for (int kk = 0; kk < 2; kk++) {
            int kb = kk * 32 + fq * 8;
            union { uint4 u; bf16x8 v; } ua, ub;
            ua.u = *(const uint4*)&As[wr * 16 + fr][kb];
            ub.u = *(const uint4*)&Ws[wc * 16 + fr][kb];
            acc = __builtin_amdgcn_mfma_f32_16x16x32_bf16(ua.v, ub.v, acc, 0, 0, 0);
        }
        __syncthreads();
    }
    int mbase = bm + wr * 16 + fq * 4;
    int n = bn + wc * 16 + fr;
    float bv = bias[n];
    #pragma unroll
    for (int r = 0; r < 4; r++) {
        int m = mbase + r;
        float v = acc[r] + bv;
        if (EPI == 1) v = v * 0.5f * (1.0f + erff(v * 0.70710678118654752f));
        if (EPI == 2) v += res[(size_t)m * N + n];
        if constexpr (sizeof(OutT) == 2) C[(size_t)m * N + n] = __float2bfloat16(v);
        else                             C[(size_t)m * N + n] = v;
    }
}

// ---------------- neighborhood attention, shared K/V LDS buffer --------------
// R14-exact (80B rows, fixed 16B slots, conflict-free b128; setprio on
// compute clusters).
__global__ __launch_bounds__(512, 4) void attn_kernel(const float* __restrict__ qkv,
                                                      const float* __restrict__ rpb,
                                                      const float* __restrict__ lrm,
                                                      __hip_bfloat16* __restrict__ out) {
    __shared__ __align__(16) unsigned KVd[KTAP * WW * 20];   // 66560 B
    __shared__ float rpbs[625];
    __shared__ float kers[NTAPS];

    int tid = threadIdx.x;
    int h = blockIdx.x >> 3;
    int n = blockIdx.x & 7;
    int q = tid >> 3;          // query column 0..63
    int c = tid & 7;           // tap-slice 0..7
    int shh = win_start(h, HH);
    int ph  = pb_start(h, HH);
    int sww = win_start(q, WW);
    int pwq = pb_start(q, WW);
    int mrow = h * WW + q;

    for (int i = tid; i < 625; i += 512) rpbs[i] = rpb[n * 625 + i];
    if (tid < NTAPS) {
        int ti = tid / KTAP, tj = tid - KTAP * ti;
        float dx = (float)(tj - NB), dy = (float)(ti - NB);
        kers[tid] = __expf(-(dx * dx + dy * dy) * (1.0f / 162.0f)) + lrm[tid] * 10.0f;
    }

    // ---- issue K loads (to regs) + Q loads ----
    float4 kreg[14], qv[8];
    #pragma unroll
    for (int it = 0; it < 7; ++it) {
        int tau = tid + 512 * it;
        if (tau < 3328) {                   // 832 rows x 4 sixteen-byte chunks
            int row = tau >> 2, j = tau & 3;
            int ti0 = row >> 6, col = row & 63;
            int ihr = shh + DIL * ti0;
            const float4* g = (const float4*)(qkv + (size_t)(ihr * WW + col) * 768
                                              + DIMC + n * HD + 8 * j);
            kreg[2 * it] = g[0]; kreg[2 * it + 1] = g[1];
        }
    }
    {
        const float4* qg = (const float4*)(qkv + (size_t)mrow * 768 + n * HD);
        #pragma unroll
        for (int i = 0; i < 8; ++i) qv[i] = qg[i];
    }

    // ---- cvt + write K (one b128 per thread-chunk, fixed slot j) ----
    #pragma unroll
    for (int it = 0; it < 7; ++it) {
        int tau = tid + 512 * it;
        if (tau < 3328) {
            int row = tau >> 2, j = tau & 3;
            float4 u0 = kreg[2 * it], u1 = kreg[2 * it + 1];
            uint4 w;
            w.x = __builtin_bit_cast(unsigned, pkh(u0.x, u0.y));
            w.y = __builtin_bit_cast(unsigned, pkh(u0.z, u0.w));
            w.z = __builtin_bit_cast(unsigned, pkh(u1.x, u1.y));
            w.w = __builtin_bit_cast(unsigned, pkh(u1.z, u1.w));
            *(uint4*)&KVd[row * 20 + j * 4] = w;
        }
    }
    // ---- pack Q (scaled) ----
    f16x2 qh[16];
    #pragma unroll
    for (int i = 0; i < 8; ++i) {
        qh[2 * i]     = pkh(qv[i].x * QSCALE, qv[i].y * QSCALE);
        qh[2 * i + 1] = pkh(qv[i].z * QSCALE, qv[i].w * QSCALE);
    }
    __syncthreads();   // #1: K + rpbs + kers visible

    // ---- issue V half-A loads (tau 0..1535, always in range) ----
    float4 vA[6];
    #pragma unroll
    for (int it = 0; it < 3; ++it) {
        int tau = tid + 512 * it;
        int row = tau >> 2, j = tau & 3;
        int ti0 = row >> 6, col = row & 63;
        int ihr = shh + DIL * ti0;
        const float4* g = (const float4*)(qkv + (size_t)(ihr * WW + col) * 768
                                          + 2 * DIMC + n * HD + 8 * j);
        vA[2 * it] = g[0]; vA[2 * it + 1] = g[1];
    }

    // ---- scores: taps t = c + 8k; incremental (ti,tj,row); b128 reads ----
    float p[22];
    float smax = -1e30f;
    __builtin_amdgcn_s_setprio(1);
    {
        int ti = 0, tj = c, tt = c;
        int row = sww + 3 * c;             // ti*64 + col, ti=0 initially
        #pragma unroll
        for (int k = 0; k < 22; ++k) {
            if (tt < NTAPS) {
                const unsigned* kp = KVd + row * 20;
                uint4 r0 = *(const uint4*)(kp);
                uint4 r1 = *(const uint4*)(kp + 4);
                uint4 r2 = *(const uint4*)(kp + 8);
                uint4 r3 = *(const uint4*)(kp + 12);
                f16x2 sa = {}, sb = {}, sc2 = {}, sd = {};
                sa  += qh[0]  * bch(r0.x); sb  += qh[1]  * bch(r0.y);
                sc2 += qh[2]  * bch(r0.z); sd  += qh[3]  * bch(r0.w);
                sa  += qh[4]  * bch(r1.x); sb  += qh[5]  * bch(r1.y);
                sc2 += qh[6]  * bch(r1.z); sd  += qh[7]  * bch(r1.w);
                sa  += qh[8]  * bch(r2.x); sb  += qh[9]  * bch(r2.y);
                sc2 += qh[10] * bch(r2.z); sd  += qh[11] * bch(r2.w);
                sa  += qh[12] * bch(r3.x); sb  += qh[13] * bch(r3.y);
                sc2 += qh[14] * bch(r3.z); sd  += qh[15] * bch(r3.w);
                f16x2 st = (sa + sb) + (sc2 + sd);
                float s = (float)st.x + (float)st.y;
                s += rpbs[(ph + ti) * 25 + pwq + tj];
                s *= kers[tt];
                p[k] = s;
                smax = fmaxf(smax, s);
            } else {
                p[k] = -1e30f;
            }
            tj += 8; row += 24;
            if (tj >= KTAP) { tj -= KTAP; ++ti; row += 25; }  // +64 (ti) -39 (col)
            tt += 8;
        }
    }
    __builtin_amdgcn_s_setprio(0);
    __syncthreads();   // #2: ALL K reads complete before V overwrites KVd

    // ---- write V half-A (loads were in flight across the score phase) ----
    #pragma unroll
    for (int it = 0; it < 3; ++it) {
        int tau = tid + 512 * it;
        int row = tau >> 2, j = tau & 3;
        float4 u0 = vA[2 * it], u1 = vA[2 * it + 1];
        uint4 w;
        w.x = __builtin_bit_cast(unsigned, pkh(u0.x, u0.y));
        w.y = __builtin_bit_cast(unsigned, pkh(u0.z, u0.w));
        w.z = __builtin_bit_cast(unsigned, pkh(u1.x, u1.y));
        w.w = __builtin_bit_cast(unsigned, pkh(u1.z, u1.w));
        *(uint4*)&KVd[row * 20 + j * 4] = w;
    }
    // ---- issue V half-B loads (tau 1536..3327) ----
    float4 vB[8];
    #pragma unroll
    for (int it = 3; it < 7; ++it) {
        int tau = tid + 512 * it;
        if (tau < 3328) {
            int row = tau >> 2, j = tau & 3;
            int ti0 = row >> 6, col = row & 63;
            int ihr = shh + DIL * ti0;
            const float4* g = (const float4*)(qkv + (size_t)(ihr * WW + col) * 768
                                              + 2 * DIMC + n * HD + 8 * j);
            vB[2 * (it - 3)] = g[0]; vB[2 * (it - 3) + 1] = g[1];
        }
    }

    // ---- softmax across the 8 c-lanes (register-only; hides vB latency) ----
    #pragma unroll
    for (int o = 1; o < 8; o <<= 1) smax = fmaxf(smax, __shfl_xor(smax, o));
    float ssum = 0.0f;
    #pragma unroll
    for (int k = 0; k < 22; ++k) {
        float e = __expf(p[k] - smax);
        p[k] = e;
        ssum += e;
    }
    #pragma unroll
    for (int o = 1; o < 8; o <<= 1) ssum += __shfl_xor(ssum, o);
    float inv = 1.0f / ssum;
    #pragma unroll
    for (int k = 0; k < 22; ++k) p[k] *= inv;

    // ---- write V half-B ----
    #pragma unroll
    for (int it = 3; it < 7; ++it) {
        int tau = tid + 512 * it;
        if (tau < 3328) {
            int row = tau >> 2, j = tau & 3;
            float4 u0 = vB[2 * (it - 3)], u1 = vB[2 * (it - 3) + 1];
            uint4 w;
            w.x = __builtin_bit_cast(unsigned, pkh(u0.x, u0.y));
            w.y = __builtin_bit_cast(unsigned, pkh(u0.z, u0.w));
            w.z = __builtin_bit_cast(unsigned, pkh(u1.x, u1.y));
            w.w = __builtin_bit_cast(unsigned, pkh(u1.z, u1.w));
            *(uint4*)&KVd[row * 20 + j * 4] = w;
        }
    }
    __syncthreads();   // #3: V fully written

    // ---- PV: own taps, packed-f16 accumulate over all 32 d ----
    f16x2 acc2[16] = {};
    __builtin_amdgcn_s_setprio(1);
    {
        int ti = 0, tj = c, tt = c;
        int row = sww + 3 * c;
        #pragma unroll
        for (int k = 0; k < 22; ++k) {
            if (tt < NTAPS) {
                const unsigned* vp = KVd + row * 20;
                uint4 r0 = *(const uint4*)(vp);
                uint4 r1 = *(const uint4*)(vp + 4);
                uint4 r2 = *(const uint4*)(vp + 8);
                uint4 r3 = *(const uint4*)(vp + 12);
                f16x2 p2 = pkh(p[k], p[k]);
                acc2[0]  += p2 * bch(r0.x); acc2[1]  += p2 * bch(r0.y);
                acc2[2]  += p2 * bch(r0.z); acc2[3]  += p2 * bch(r0.w);
                acc2[4]  += p2 * bch(r1.x); acc2[5]  += p2 * bch(r1.y);
                acc2[6]  += p2 * bch(r1.z); acc2[7]  += p2 * bch(r1.w);
                acc2[8]  += p2 * bch(r2.x); acc2[9]  += p2 * bch(r2.y);
                acc2[10] += p2 * bch(r2.z); acc2[11] += p2 * bch(r2.w);
                acc2[12] += p2 * bch(r3.x); acc2[13] += p2 * bch(r3.y);
                acc2[14] += p2 * bch(r3.z); acc2[15] += p2 * bch(r3.w);
            }
            tj += 8; row += 24;
            if (tj >= KTAP) { tj -= KTAP; ++ti; row += 25; }
            tt += 8;
        }
    }
    __builtin_amdgcn_s_setprio(0);
    // ---- reduce-scatter across 8 c-lanes; lane c keeps d = 4c..4c+3 ----
    f16x2 r8v[8];
    {
        bool b = (c & 4);
        #pragma unroll
        for (int i = 0; i < 8; ++i) {
            f16x2 keep = b ? acc2[i + 8] : acc2[i];
            f16x2 send = b ? acc2[i] : acc2[i + 8];
            float sf = __shfl_xor(__builtin_bit_cast(float, send), 4);
            r8v[i] = keep + __builtin_bit_cast(f16x2, sf);
        }
    }
    f16x2 r4v[4];
    {
        bool b = (c & 2);
        #pragma unroll
        for (int i = 0; i < 4; ++i) {
            f16x2 keep = b ? r8v[i + 4] : r8v[i];
            f16x2 send = b ? r8v[i] : r8v[i + 4];
            float sf = __shfl_xor(__builtin_bit_cast(float, send), 2);
            r4v[i] = keep + __builtin_bit_cast(f16x2, sf);
        }
    }
    f16x2 r2v[2];
    {
        bool b = (c & 1);
        #pragma unroll
        for (int i = 0; i < 2; ++i) {
            f16x2 keep = b ? r4v[i + 2] : r4v[i];
            f16x2 send = b ? r4v[i] : r4v[i + 2];
            float sf = __shfl_xor(__builtin_bit_cast(float, send), 1);
            r2v[i] = keep + __builtin_bit_cast(f16x2, sf);
        }
    }
    union { __hip_bfloat16 hh[4]; ushort4 u4; } ow;
    ow.hh[0] = __float2bfloat16((float)r2v[0].x);
    ow.hh[1] = __float2bfloat16((float)r2v[0].y);
    ow.hh[2] = __float2bfloat16((float)r2v[1].x);
    ow.hh[3] = __float2bfloat16((float)r2v[1].y);
    *(ushort4*)&out[(size_t)mrow * DIMC + n * HD + c * 4] = ow.u4;
}

// ---------------- launch -----------------------------------------------------
extern "C" void kernel_launch(void* const* d_in, const int* in_sizes, int n_in,
                              void* d_out, int out_size, void* d_ws, size_t ws_size,
                              hipStream_t stream) {
    const float* x      = (const float*)d_in[0];
    const float* ln1_w  = (const float*)d_in[1];
    const float* ln1_b  = (const float*)d_in[2];
    const float* qkv_w  = (const float*)d_in[3];
    const float* qkv_b  = (const float*)d_in[4];
    const float* rpb    = (const float*)d_in[5];
    const float* lr_m   = (const float*)d_in[6];
    const float* proj_w = (const float*)d_in[7];
    const float* proj_b = (const float*)d_in[8];
    const float* ln2_w  = (const float*)d_in[9];
    const float* ln2_b  = (const float*)d_in[10];
    const float* fc1_w  = (const float*)d_in[11];
    const float* fc1_b  = (const float*)d_in[12];
    const float* fc2_w  = (const float*)d_in[13];
    const float* fc2_b  = (const float*)d_in[14];
    const float* nf_w   = (const float*)d_in[15];
    const float* nf_b   = (const float*)d_in[16];
    float* out = (float*)d_out;

    char* ws = (char*)d_ws;
    float*          t        = (float*)ws;                               //  3 MB
    float*          qkvb     = (float*)(ws + 3145728);                   //  9.4 MB
    __hip_bfloat16* y        = (__hip_bfloat16*)(ws + 12582912);         //  1.5 MB
    __hip_bfloat16* attn_out = (__hip_bfloat16*)(ws + 14155776);         //  1.5 MB
    __hip_bfloat16* m1       = (__hip_bfloat16*)(ws + 15728640);         //  6 MB
    __hip_bfloat16* qkv_wb   = (__hip_bfloat16*)(ws + 22020096);         //  2.25 MB
    __hip_bfloat16* proj_wb  = (__hip_bfloat16*)(ws + 24379392);         //  0.75 MB
    __hip_bfloat16* fc1_wb   = (__hip_bfloat16*)(ws + 25165824);         //  3 MB
    __hip_bfloat16* fc2_wb   = (__hip_bfloat16*)(ws + 28311552);         //  3 MB

    // one launch converts all 4 weight buffers (1179648 float4s total)
    cvt_all_kernel<<<1179648 / 256, 256, 0, stream>>>(
        qkv_w, proj_w, fc1_w, fc2_w, qkv_wb, proj_wb, fc1_wb, fc2_wb);

    transpose_in_kernel<<<MROWS, 256, 0, stream>>>(x, t);

    for (int l = 0; l < 6; l++) {
        const __hip_bfloat16* qw  = qkv_wb  + (size_t)l * 768 * 256;
        const __hip_bfloat16* pw  = proj_wb + (size_t)l * 256 * 256;
        const __hip_bfloat16* f1w = fc1_wb  + (size_t)l * 1024 * 256;
        const __hip_bfloat16* f2w = fc2_wb  + (size_t)l * 256 * 1024;
        const float* qb  = qkv_b  + (size_t)l * 768;
        const float* pb  = proj_b + (size_t)l * 256;
        const float* f1b = fc1_b  + (size_t)l * 1024;
        const float* f2b = fc2_b  + (size_t)l * 256;
        const float* rp  = rpb    + (size_t)l * NHEADS * 25 * 25;
        const float* lm  = lr_m   + (size_t)l * NTAPS;

        ln_kernel<__hip_bfloat16, 0><<<MROWS, 256, 0, stream>>>(
            t, ln1_w + l * 256, ln1_b + l * 256, y);
        gemm_mfma_kernel<0, float><<<dim3(768 / 64, MROWS / 64), 1024, 0, stream>>>(
            y, qw, qb, nullptr, qkvb, MROWS, 768, 256);
        attn_kernel<<<HH * NHEADS, 512, 0, stream>>>(qkvb, rp, lm, attn_out);
        gemm_mfma_kernel<2, float><<<dim3(256 / 64, MROWS / 64), 1024, 0, stream>>>(
            attn_out, pw, pb, t, t, MROWS, 256, 256);
        ln_kernel<__hip_bfloat16, 0><<<MROWS, 256, 0, stream>>>(
            t, ln2_w + l * 256, ln2_b + l * 256, y);
        gemm_mfma_kernel<1, __hip_bfloat16><<<dim3(1024 / 64, MROWS / 64), 1024, 0, stream>>>(
            y, f1w, f1b, nullptr, m1, MROWS, 1024, 256);
        gemm_mfma_kernel<2, float><<<dim3(256 / 64, MROWS / 64), 1024, 0, stream>>>(
            m1, f2w, f2b, t, t, MROWS, 256, 1024);
    }

    ln_kernel<float, 1><<<MROWS, 256, 0, stream>>>(t, nf_w, nf_b, out);
}

// Round 19
// 387.255 us; speedup vs baseline: 1.0450x; 1.0450x over previous
//
#include <hip/hip_runtime.h>
#include <hip/hip_bf16.h>
#include <math.h>

// Problem constants (compile-time)
#define DIMC   256
#define HH     48
#define WW     64
#define MROWS  (HH*WW)     // 3072
#define NHEADS 8
#define HD     32
#define KTAP   13
#define NTAPS  (KTAP*KTAP) // 169
#define DIL    3
#define NB     6           // KTAP/2
#define EPSLN  1e-5f
#define QSCALE 0.17677669529663687f  // 32^-0.5

typedef __attribute__((ext_vector_type(8))) short bf16x8;
typedef __attribute__((ext_vector_type(4))) float f32x4;
typedef _Float16 __f16;
typedef __f16 f16x2 __attribute__((ext_vector_type(2)));

__device__ __forceinline__ f16x2 pkh(float a, float b) {
    auto r = __builtin_amdgcn_cvt_pkrtz(a, b);
    return __builtin_bit_cast(f16x2, r);
}
__device__ __forceinline__ f16x2 bch(unsigned u) {
    return __builtin_bit_cast(f16x2, u);
}

// ---------------- window/bias start helpers (static arithmetic) -------------
__device__ __forceinline__ int win_start(int i, int L) {
    int imodd = i % DIL;
    if (i - NB * DIL < 0) return imodd;
    if (i + NB * DIL >= L) {
        int a = (L / DIL) * DIL;
        int b = L - a;
        if (imodd < b) return L - b + imodd - 2 * NB * DIL;
        return a + imodd - KTAP * DIL;
    }
    return i - NB * DIL;
}
__device__ __forceinline__ int pb_start(int i, int L) {
    if (i - NB * DIL < 0) return KTAP - 1 - i / DIL;
    if (i + NB * DIL >= L) return (L - 1 - i) / DIL;
    return NB;
}

// ---------------- fp32 -> bf16 conversion, all 4 weight buffers in 1 launch --
__global__ __launch_bounds__(256) void cvt_all_kernel(const float* __restrict__ w0,
                                                      const float* __restrict__ w1,
                                                      const float* __restrict__ w2,
                                                      const float* __restrict__ w3,
                                                      __hip_bfloat16* __restrict__ o0,
                                                      __hip_bfloat16* __restrict__ o1,
                                                      __hip_bfloat16* __restrict__ o2,
                                                      __hip_bfloat16* __restrict__ o3) {
    int i = blockIdx.x * 256 + threadIdx.x;
    const float* in;
    __hip_bfloat16* out;
    int off;
    if (i < 294912)      { in = w0; out = o0; off = i; }
    else if (i < 393216) { in = w1; out = o1; off = i - 294912; }
    else if (i < 786432) { in = w2; out = o2; off = i - 393216; }
    else                 { in = w3; out = o3; off = i - 786432; }
    float4 v = ((const float4*)in)[off];
    union { __hip_bfloat16 h[4]; ushort4 u; } p;
    p.h[0] = __float2bfloat16(v.x);
    p.h[1] = __float2bfloat16(v.y);
    p.h[2] = __float2bfloat16(v.z);
    p.h[3] = __float2bfloat16(v.w);
    ((ushort4*)out)[off] = p.u;
}

// ---------------- input transpose: x (C, H*W) -> t (H*W, C) -----------------
__global__ void transpose_in_kernel(const float* __restrict__ x, float* __restrict__ t) {
    int m = blockIdx.x;
    int c = threadIdx.x;
    t[m * DIMC + c] = x[c * MROWS + m];
}

// ---------------- layernorm; OutT float or bf16; optional transposed store ---
template <typename OutT, int TRANS>
__global__ __launch_bounds__(256) void ln_kernel(const float* __restrict__ in,
                                                 const float* __restrict__ w,
                                                 const float* __restrict__ b,
                                                 OutT* __restrict__ out) {
    __shared__ float s1[4], s2[4];
    int m = blockIdx.x;
    int c = threadIdx.x;
    float v = in[m * DIMC + c];
    float a = v, q = v * v;
    #pragma unroll
    for (int o = 32; o > 0; o >>= 1) {
        a += __shfl_xor(a, o);
        q += __shfl_xor(q, o);
    }
    if ((threadIdx.x & 63) == 0) { s1[threadIdx.x >> 6] = a; s2[threadIdx.x >> 6] = q; }
    __syncthreads();
    float mean = (s1[0] + s1[1] + s1[2] + s1[3]) * (1.0f / DIMC);
    float var  = (s2[0] + s2[1] + s2[2] + s2[3]) * (1.0f / DIMC) - mean * mean;
    float r = (v - mean) * rsqrtf(var + EPSLN) * w[c] + b[c];
    if (TRANS) {
        out[c * MROWS + m] = (OutT)r;
    } else {
        if constexpr (sizeof(OutT) == 2) out[m * DIMC + c] = __float2bfloat16(r);
        else                             out[m * DIMC + c] = r;
    }
}

// ---------------- bf16 MFMA GEMM: C = A * W^T + bias -------------------------
// 18.4 KB LDS, 512 threads / 8 waves per 64x64 tile (wave = 16x32 sub-tile):
// R16-proven optimum (1-wave/SIMD:397, 2:387, 4:405). Register double-buffer.
#define LDP 72
template <int EPI, typename OutT>
__global__ __launch_bounds__(512) void gemm_mfma_kernel(const __hip_bfloat16* __restrict__ A,
                                                        const __hip_bfloat16* __restrict__ Wt,
                                                        const float* __restrict__ bias,
                                                        const float* __restrict__ res,
                                                        OutT* __restrict__ C,
                                                        int M, int N, int K) {
    __shared__ __hip_bfloat16 As[64][LDP];
    __shared__ __hip_bfloat16 Ws[64][LDP];
    int tid = threadIdx.x;
    int bm = blockIdx.y * 64, bn = blockIdx.x * 64;
    int lane = tid & 63, wid = tid >> 6;      // 8 waves
    int wr = wid >> 1, wc = wid & 1;          // wave: rows wr*16, cols wc*32
    int fr = lane & 15, fq = lane >> 4;
    f32x4 acc[2] = {};

    // prologue: load tile 0 into registers (2 x uint2 per thread)
    uint2 ra[2], rw[2];
    #pragma unroll
    for (int i = 0; i < 2; i++) {
        int idx = tid + i * 512;
        int r = idx >> 4, c = (idx & 15) << 2;
        ra[i] = *(const uint2*)&A[(size_t)(bm + r) * K + c];
        rw[i] = *(const uint2*)&Wt[(size_t)(bn + r) * K + c];
    }

    for (int k0 = 0; k0 < K; k0 += 64) {
        #pragma unroll
        for (int i = 0; i < 2; i++) {
            int idx = tid + i * 512;
            int r = idx >> 4, c = (idx & 15) << 2;
            *(uint2*)&As[r][c] = ra[i];
            *(uint2*)&Ws[r][c] = rw[i];
        }
        __syncthreads();
        if (k0 + 64 < K) {
            #pragma unroll
            for (int i = 0; i < 2; i++) {
                int idx = tid + i * 512;
                int r = idx >> 4, c = (idx & 15) << 2;
                ra[i] = *(const uint2*)&A[(size_t)(bm + r) * K + k0 + 64 + c];
                rw[i] = *(const uint2*)&Wt[(size_t)(bn + r) * K + k0 + 64 + c];
            }
        }
        #pragma unroll
        for (int kk = 0; kk < 2; kk++) {
            int kb = kk * 32 + fq * 8;
            bf16x8 af;
            {
                union { uint4 u; bf16x8 v; } ua;
                ua.u = *(const uint4*)&As[wr * 16 + fr][kb];
                af = ua.v;
            }
            #pragma unroll
            for (int j = 0; j < 2; j++) {
                union { uint4 u; bf16x8 v; } ub;
                ub.u = *(const uint4*)&Ws[wc * 32 + j * 16 + fr][kb];
                acc[j] = __builtin_amdgcn_mfma_f32_16x16x32_bf16(af, ub.v, acc[j], 0, 0, 0);
            }
        }
        __syncthreads();
    }
    int mbase = bm + wr * 16 + fq * 4;
    #pragma unroll
    for (int j = 0; j < 2; j++) {
        int n = bn + wc * 32 + j * 16 + fr;
        float bv = bias[n];
        #pragma unroll
        for (int r = 0; r < 4; r++) {
            int m = mbase + r;
            float v = acc[j][r] + bv;
            if (EPI == 1) v = v * 0.5f * (1.0f + erff(v * 0.70710678118654752f));
            if (EPI == 2) v += res[(size_t)m * N + n];
            if constexpr (sizeof(OutT) == 2) C[(size_t)m * N + n] = __float2bfloat16(v);
            else                             C[(size_t)m * N + n] = v;
        }
    }
}

// ---------------- neighborhood attention, shared K/V LDS buffer --------------
// R14-exact (80B rows, fixed 16B slots, conflict-free b128; setprio on
// compute clusters).
__global__ __launch_bounds__(512, 4) void attn_kernel(const float* __restrict__ qkv,
                                                      const float* __restrict__ rpb,
                                                      const float* __restrict__ lrm,
                                                      __hip_bfloat16* __restrict__ out) {
    __shared__ __align__(16) unsigned KVd[KTAP * WW * 20];   // 66560 B
    __shared__ float rpbs[625];
    __shared__ float kers[NTAPS];

    int tid = threadIdx.x;
    int h = blockIdx.x >> 3;
    int n = blockIdx.x & 7;
    int q = tid >> 3;          // query column 0..63
    int c = tid & 7;           // tap-slice 0..7
    int shh = win_start(h, HH);
    int ph  = pb_start(h, HH);
    int sww = win_start(q, WW);
    int pwq = pb_start(q, WW);
    int mrow = h * WW + q;

    for (int i = tid; i < 625; i += 512) rpbs[i] = rpb[n * 625 + i];
    if (tid < NTAPS) {
        int ti = tid / KTAP, tj = tid - KTAP * ti;
        float dx = (float)(tj - NB), dy = (float)(ti - NB);
        kers[tid] = __expf(-(dx * dx + dy * dy) * (1.0f / 162.0f)) + lrm[tid] * 10.0f;
    }

    // ---- issue K loads (to regs) + Q loads ----
    float4 kreg[14], qv[8];
    #pragma unroll
    for (int it = 0; it < 7; ++it) {
        int tau = tid + 512 * it;
        if (tau < 3328) {                   // 832 rows x 4 sixteen-byte chunks
            int row = tau >> 2, j = tau & 3;
            int ti0 = row >> 6, col = row & 63;
            int ihr = shh + DIL * ti0;
            const float4* g = (const float4*)(qkv + (size_t)(ihr * WW + col) * 768
                                              + DIMC + n * HD + 8 * j);
            kreg[2 * it] = g[0]; kreg[2 * it + 1] = g[1];
        }
    }
    {
        const float4* qg = (const float4*)(qkv + (size_t)mrow * 768 + n * HD);
        #pragma unroll
        for (int i = 0; i < 8; ++i) qv[i] = qg[i];
    }

    // ---- cvt + write K (one b128 per thread-chunk, fixed slot j) ----
    #pragma unroll
    for (int it = 0; it < 7; ++it) {
        int tau = tid + 512 * it;
        if (tau < 3328) {
            int row = tau >> 2, j = tau & 3;
            float4 u0 = kreg[2 * it], u1 = kreg[2 * it + 1];
            uint4 w;
            w.x = __builtin_bit_cast(unsigned, pkh(u0.x, u0.y));
            w.y = __builtin_bit_cast(unsigned, pkh(u0.z, u0.w));
            w.z = __builtin_bit_cast(unsigned, pkh(u1.x, u1.y));
            w.w = __builtin_bit_cast(unsigned, pkh(u1.z, u1.w));
            *(uint4*)&KVd[row * 20 + j * 4] = w;
        }
    }
    // ---- pack Q (scaled) ----
    f16x2 qh[16];
    #pragma unroll
    for (int i = 0; i < 8; ++i) {
        qh[2 * i]     = pkh(qv[i].x * QSCALE, qv[i].y * QSCALE);
        qh[2 * i + 1] = pkh(qv[i].z * QSCALE, qv[i].w * QSCALE);
    }
    __syncthreads();   // #1: K + rpbs + kers visible

    // ---- issue V half-A loads (tau 0..1535, always in range) ----
    float4 vA[6];
    #pragma unroll
    for (int it = 0; it < 3; ++it) {
        int tau = tid + 512 * it;
        int row = tau >> 2, j = tau & 3;
        int ti0 = row >> 6, col = row & 63;
        int ihr = shh + DIL * ti0;
        const float4* g = (const float4*)(qkv + (size_t)(ihr * WW + col) * 768
                                          + 2 * DIMC + n * HD + 8 * j);
        vA[2 * it] = g[0]; vA[2 * it + 1] = g[1];
    }

    // ---- scores: taps t = c + 8k; incremental (ti,tj,row); b128 reads ----
    float p[22];
    float smax = -1e30f;
    __builtin_amdgcn_s_setprio(1);
    {
        int ti = 0, tj = c, tt = c;
        int row = sww + 3 * c;             // ti*64 + col, ti=0 initially
        #pragma unroll
        for (int k = 0; k < 22; ++k) {
            if (tt < NTAPS) {
                const unsigned* kp = KVd + row * 20;
                uint4 r0 = *(const uint4*)(kp);
                uint4 r1 = *(const uint4*)(kp + 4);
                uint4 r2 = *(const uint4*)(kp + 8);
                uint4 r3 = *(const uint4*)(kp + 12);
                f16x2 sa = {}, sb = {}, sc2 = {}, sd = {};
                sa  += qh[0]  * bch(r0.x); sb  += qh[1]  * bch(r0.y);
                sc2 += qh[2]  * bch(r0.z); sd  += qh[3]  * bch(r0.w);
                sa  += qh[4]  * bch(r1.x); sb  += qh[5]  * bch(r1.y);
                sc2 += qh[6]  * bch(r1.z); sd  += qh[7]  * bch(r1.w);
                sa  += qh[8]  * bch(r2.x); sb  += qh[9]  * bch(r2.y);
                sc2 += qh[10] * bch(r2.z); sd  += qh[11] * bch(r2.w);
                sa  += qh[12] * bch(r3.x); sb  += qh[13] * bch(r3.y);
                sc2 += qh[14] * bch(r3.z); sd  += qh[15] * bch(r3.w);
                f16x2 st = (sa + sb) + (sc2 + sd);
                float s = (float)st.x + (float)st.y;
                s += rpbs[(ph + ti) * 25 + pwq + tj];
                s *= kers[tt];
                p[k] = s;
                smax = fmaxf(smax, s);
            } else {
                p[k] = -1e30f;
            }
            tj += 8; row += 24;
            if (tj >= KTAP) { tj -= KTAP; ++ti; row += 25; }  // +64 (ti) -39 (col)
            tt += 8;
        }
    }
    __builtin_amdgcn_s_setprio(0);
    __syncthreads();   // #2: ALL K reads complete before V overwrites KVd

    // ---- write V half-A (loads were in flight across the score phase) ----
    #pragma unroll
    for (int it = 0; it < 3; ++it) {
        int tau = tid + 512 * it;
        int row = tau >> 2, j = tau & 3;
        float4 u0 = vA[2 * it], u1 = vA[2 * it + 1];
        uint4 w;
        w.x = __builtin_bit_cast(unsigned, pkh(u0.x, u0.y));
        w.y = __builtin_bit_cast(unsigned, pkh(u0.z, u0.w));
        w.z = __builtin_bit_cast(unsigned, pkh(u1.x, u1.y));
        w.w = __builtin_bit_cast(unsigned, pkh(u1.z, u1.w));
        *(uint4*)&KVd[row * 20 + j * 4] = w;
    }
    // ---- issue V half-B loads (tau 1536..3327) ----
    float4 vB[8];
    #pragma unroll
    for (int it = 3; it < 7; ++it) {
        int tau = tid + 512 * it;
        if (tau < 3328) {
            int row = tau >> 2, j = tau & 3;
            int ti0 = row >> 6, col = row & 63;
            int ihr = shh + DIL * ti0;
            const float4* g = (const float4*)(qkv + (size_t)(ihr * WW + col) * 768
                                              + 2 * DIMC + n * HD + 8 * j);
            vB[2 * (it - 3)] = g[0]; vB[2 * (it - 3) + 1] = g[1];
        }
    }

    // ---- softmax across the 8 c-lanes (register-only; hides vB latency) ----
    #pragma unroll
    for (int o = 1; o < 8; o <<= 1) smax = fmaxf(smax, __shfl_xor(smax, o));
    float ssum = 0.0f;
    #pragma unroll
    for (int k = 0; k < 22; ++k) {
        float e = __expf(p[k] - smax);
        p[k] = e;
        ssum += e;
    }
    #pragma unroll
    for (int o = 1; o < 8; o <<= 1) ssum += __shfl_xor(ssum, o);
    float inv = 1.0f / ssum;
    #pragma unroll
    for (int k = 0; k < 22; ++k) p[k] *= inv;

    // ---- write V half-B ----
    #pragma unroll
    for (int it = 3; it < 7; ++it) {
        int tau = tid + 512 * it;
        if (tau < 3328) {
            int row = tau >> 2, j = tau & 3;
            float4 u0 = vB[2 * (it - 3)], u1 = vB[2 * (it - 3) + 1];
            uint4 w;
            w.x = __builtin_bit_cast(unsigned, pkh(u0.x, u0.y));
            w.y = __builtin_bit_cast(unsigned, pkh(u0.z, u0.w));
            w.z = __builtin_bit_cast(unsigned, pkh(u1.x, u1.y));
            w.w = __builtin_bit_cast(unsigned, pkh(u1.z, u1.w));
            *(uint4*)&KVd[row * 20 + j * 4] = w;
        }
    }
    __syncthreads();   // #3: V fully written

    // ---- PV: own taps, packed-f16 accumulate over all 32 d ----
    f16x2 acc2[16] = {};
    __builtin_amdgcn_s_setprio(1);
    {
        int ti = 0, tj = c, tt = c;
        int row = sww + 3 * c;
        #pragma unroll
        for (int k = 0; k < 22; ++k) {
            if (tt < NTAPS) {
                const unsigned* vp = KVd + row * 20;
                uint4 r0 = *(const uint4*)(vp);
                uint4 r1 = *(const uint4*)(vp + 4);
                uint4 r2 = *(const uint4*)(vp + 8);
                uint4 r3 = *(const uint4*)(vp + 12);
                f16x2 p2 = pkh(p[k], p[k]);
                acc2[0]  += p2 * bch(r0.x); acc2[1]  += p2 * bch(r0.y);
                acc2[2]  += p2 * bch(r0.z); acc2[3]  += p2 * bch(r0.w);
                acc2[4]  += p2 * bch(r1.x); acc2[5]  += p2 * bch(r1.y);
                acc2[6]  += p2 * bch(r1.z); acc2[7]  += p2 * bch(r1.w);
                acc2[8]  += p2 * bch(r2.x); acc2[9]  += p2 * bch(r2.y);
                acc2[10] += p2 * bch(r2.z); acc2[11] += p2 * bch(r2.w);
                acc2[12] += p2 * bch(r3.x); acc2[13] += p2 * bch(r3.y);
                acc2[14] += p2 * bch(r3.z); acc2[15] += p2 * bch(r3.w);
            }
            tj += 8; row += 24;
            if (tj >= KTAP) { tj -= KTAP; ++ti; row += 25; }
            tt += 8;
        }
    }
    __builtin_amdgcn_s_setprio(0);
    // ---- reduce-scatter across 8 c-lanes; lane c keeps d = 4c..4c+3 ----
    f16x2 r8v[8];
    {
        bool b = (c & 4);
        #pragma unroll
        for (int i = 0; i < 8; ++i) {
            f16x2 keep = b ? acc2[i + 8] : acc2[i];
            f16x2 send = b ? acc2[i] : acc2[i + 8];
            float sf = __shfl_xor(__builtin_bit_cast(float, send), 4);
            r8v[i] = keep + __builtin_bit_cast(f16x2, sf);
        }
    }
    f16x2 r4v[4];
    {
        bool b = (c & 2);
        #pragma unroll
        for (int i = 0; i < 4; ++i) {
            f16x2 keep = b ? r8v[i + 4] : r8v[i];
            f16x2 send = b ? r8v[i] : r8v[i + 4];
            float sf = __shfl_xor(__builtin_bit_cast(float, send), 2);
            r4v[i] = keep + __builtin_bit_cast(f16x2, sf);
        }
    }
    f16x2 r2v[2];
    {
        bool b = (c & 1);
        #pragma unroll
        for (int i = 0; i < 2; ++i) {
            f16x2 keep = b ? r4v[i + 2] : r4v[i];
            f16x2 send = b ? r4v[i] : r4v[i + 2];
            float sf = __shfl_xor(__builtin_bit_cast(float, send), 1);
            r2v[i] = keep + __builtin_bit_cast(f16x2, sf);
        }
    }
    union { __hip_bfloat16 hh[4]; ushort4 u4; } ow;
    ow.hh[0] = __float2bfloat16((float)r2v[0].x);
    ow.hh[1] = __float2bfloat16((float)r2v[0].y);
    ow.hh[2] = __float2bfloat16((float)r2v[1].x);
    ow.hh[3] = __float2bfloat16((float)r2v[1].y);
    *(ushort4*)&out[(size_t)mrow * DIMC + n * HD + c * 4] = ow.u4;
}

// ---------------- launch -----------------------------------------------------
extern "C" void kernel_launch(void* const* d_in, const int* in_sizes, int n_in,
                              void* d_out, int out_size, void* d_ws, size_t ws_size,
                              hipStream_t stream) {
    const float* x      = (const float*)d_in[0];
    const float* ln1_w  = (const float*)d_in[1];
    const float* ln1_b  = (const float*)d_in[2];
    const float* qkv_w  = (const float*)d_in[3];
    const float* qkv_b  = (const float*)d_in[4];
    const float* rpb    = (const float*)d_in[5];
    const float* lr_m   = (const float*)d_in[6];
    const float* proj_w = (const float*)d_in[7];
    const float* proj_b = (const float*)d_in[8];
    const float* ln2_w  = (const float*)d_in[9];
    const float* ln2_b  = (const float*)d_in[10];
    const float* fc1_w  = (const float*)d_in[11];
    const float* fc1_b  = (const float*)d_in[12];
    const float* fc2_w  = (const float*)d_in[13];
    const float* fc2_b  = (const float*)d_in[14];
    const float* nf_w   = (const float*)d_in[15];
    const float* nf_b   = (const float*)d_in[16];
    float* out = (float*)d_out;

    char* ws = (char*)d_ws;
    float*          t        = (float*)ws;                               //  3 MB
    float*          qkvb     = (float*)(ws + 3145728);                   //  9.4 MB
    __hip_bfloat16* y        = (__hip_bfloat16*)(ws + 12582912);         //  1.5 MB
    __hip_bfloat16* attn_out = (__hip_bfloat16*)(ws + 14155776);         //  1.5 MB
    __hip_bfloat16* m1       = (__hip_bfloat16*)(ws + 15728640);         //  6 MB
    __hip_bfloat16* qkv_wb   = (__hip_bfloat16*)(ws + 22020096);         //  2.25 MB
    __hip_bfloat16* proj_wb  = (__hip_bfloat16*)(ws + 24379392);         //  0.75 MB
    __hip_bfloat16* fc1_wb   = (__hip_bfloat16*)(ws + 25165824);         //  3 MB
    __hip_bfloat16* fc2_wb   = (__hip_bfloat16*)(ws + 28311552);         //  3 MB

    // one launch converts all 4 weight buffers (1179648 float4s total)
    cvt_all_kernel<<<1179648 / 256, 256, 0, stream>>>(
        qkv_w, proj_w, fc1_w, fc2_w, qkv_wb, proj_wb, fc1_wb, fc2_wb);

    transpose_in_kernel<<<MROWS, 256, 0, stream>>>(x, t);

    for (int l = 0; l < 6; l++) {
        const __hip_bfloat16* qw  = qkv_wb  + (size_t)l * 768 * 256;
        const __hip_bfloat16* pw  = proj_wb + (size_t)l * 256 * 256;
        const __hip_bfloat16* f1w = fc1_wb  + (size_t)l * 1024 * 256;
        const __hip_bfloat16* f2w = fc2_wb  + (size_t)l * 256 * 1024;
        const float* qb  = qkv_b  + (size_t)l * 768;
        const float* pb  = proj_b + (size_t)l * 256;
        const float* f1b = fc1_b  + (size_t)l * 1024;
        const float* f2b = fc2_b  + (size_t)l * 256;
        const float* rp  = rpb    + (size_t)l * NHEADS * 25 * 25;
        const float* lm  = lr_m   + (size_t)l * NTAPS;

        ln_kernel<__hip_bfloat16, 0><<<MROWS, 256, 0, stream>>>(
            t, ln1_w + l * 256, ln1_b + l * 256, y);
        gemm_mfma_kernel<0, float><<<dim3(768 / 64, MROWS / 64), 512, 0, stream>>>(
            y, qw, qb, nullptr, qkvb, MROWS, 768, 256);
        attn_kernel<<<HH * NHEADS, 512, 0, stream>>>(qkvb, rp, lm, attn_out);
        gemm_mfma_kernel<2, float><<<dim3(256 / 64, MROWS / 64), 512, 0, stream>>>(
            attn_out, pw, pb, t, t, MROWS, 256, 256);
        ln_kernel<__hip_bfloat16, 0><<<MROWS, 256, 0, stream>>>(
            t, ln2_w + l * 256, ln2_b + l * 256, y);
        gemm_mfma_kernel<1, __hip_bfloat16><<<dim3(1024 / 64, MROWS / 64), 512, 0, stream>>>(
            y, f1w, f1b, nullptr, m1, MROWS, 1024, 256);
        gemm_mfma_kernel<2, float><<<dim3(256 / 64, MROWS / 64), 512, 0, stream>>>(
            m1, f2w, f2b, t, t, MROWS, 256, 1024);
    }

    ln_kernel<float, 1><<<MROWS, 256, 0, stream>>>(t, nf_w, nf_b, out);
}

// Round 20
// 373.759 us; speedup vs baseline: 1.0828x; 1.0361x over previous
//
#include <hip/hip_runtime.h>
#include <hip/hip_bf16.h>
#include <math.h>

// Problem constants (compile-time)
#define DIMC   256
#define HH     48
#define WW     64
#define MROWS  (HH*WW)     // 3072
#define NHEADS 8
#define HD     32
#define KTAP   13
#define NTAPS  (KTAP*KTAP) // 169
#define DIL    3
#define NB     6           // KTAP/2
#define EPSLN  1e-5f
#define QSCALE 0.17677669529663687f  // 32^-0.5

typedef __attribute__((ext_vector_type(8))) short bf16x8;
typedef __attribute__((ext_vector_type(4))) float f32x4;
typedef _Float16 __f16;
typedef __f16 f16x2 __attribute__((ext_vector_type(2)));

__device__ __forceinline__ f16x2 pkh(float a, float b) {
    auto r = __builtin_amdgcn_cvt_pkrtz(a, b);
    return __builtin_bit_cast(f16x2, r);
}
__device__ __forceinline__ f16x2 bch(unsigned u) {
    return __builtin_bit_cast(f16x2, u);
}

// ---------------- window/bias start helpers (static arithmetic) -------------
__device__ __forceinline__ int win_start(int i, int L) {
    int imodd = i % DIL;
    if (i - NB * DIL < 0) return imodd;
    if (i + NB * DIL >= L) {
        int a = (L / DIL) * DIL;
        int b = L - a;
        if (imodd < b) return L - b + imodd - 2 * NB * DIL;
        return a + imodd - KTAP * DIL;
    }
    return i - NB * DIL;
}
__device__ __forceinline__ int pb_start(int i, int L) {
    if (i - NB * DIL < 0) return KTAP - 1 - i / DIL;
    if (i + NB * DIL >= L) return (L - 1 - i) / DIL;
    return NB;
}

// ---------------- fp32 -> bf16 conversion, all 4 weight buffers in 1 launch --
__global__ __launch_bounds__(256) void cvt_all_kernel(const float* __restrict__ w0,
                                                      const float* __restrict__ w1,
                                                      const float* __restrict__ w2,
                                                      const float* __restrict__ w3,
                                                      __hip_bfloat16* __restrict__ o0,
                                                      __hip_bfloat16* __restrict__ o1,
                                                      __hip_bfloat16* __restrict__ o2,
                                                      __hip_bfloat16* __restrict__ o3) {
    int i = blockIdx.x * 256 + threadIdx.x;
    const float* in;
    __hip_bfloat16* out;
    int off;
    if (i < 294912)      { in = w0; out = o0; off = i; }
    else if (i < 393216) { in = w1; out = o1; off = i - 294912; }
    else if (i < 786432) { in = w2; out = o2; off = i - 393216; }
    else                 { in = w3; out = o3; off = i - 786432; }
    float4 v = ((const float4*)in)[off];
    union { __hip_bfloat16 h[4]; ushort4 u; } p;
    p.h[0] = __float2bfloat16(v.x);
    p.h[1] = __float2bfloat16(v.y);
    p.h[2] = __float2bfloat16(v.z);
    p.h[3] = __float2bfloat16(v.w);
    ((ushort4*)out)[off] = p.u;
}

// ---------------- input transpose: x (C, H*W) -> t (H*W, C) -----------------
__global__ void transpose_in_kernel(const float* __restrict__ x, float* __restrict__ t) {
    int m = blockIdx.x;
    int c = threadIdx.x;
    t[m * DIMC + c] = x[c * MROWS + m];
}

// ---------------- layernorm; OutT float or bf16; optional transposed store ---
template <typename OutT, int TRANS>
__global__ __launch_bounds__(256) void ln_kernel(const float* __restrict__ in,
                                                 const float* __restrict__ w,
                                                 const float* __restrict__ b,
                                                 OutT* __restrict__ out) {
    __shared__ float s1[4], s2[4];
    int m = blockIdx.x;
    int c = threadIdx.x;
    float v = in[m * DIMC + c];
    float a = v, q = v * v;
    #pragma unroll
    for (int o = 32; o > 0; o >>= 1) {
        a += __shfl_xor(a, o);
        q += __shfl_xor(q, o);
    }
    if ((threadIdx.x & 63) == 0) { s1[threadIdx.x >> 6] = a; s2[threadIdx.x >> 6] = q; }
    __syncthreads();
    float mean = (s1[0] + s1[1] + s1[2] + s1[3]) * (1.0f / DIMC);
    float var  = (s2[0] + s2[1] + s2[2] + s2[3]) * (1.0f / DIMC) - mean * mean;
    float r = (v - mean) * rsqrtf(var + EPSLN) * w[c] + b[c];
    if (TRANS) {
        out[c * MROWS + m] = (OutT)r;
    } else {
        if constexpr (sizeof(OutT) == 2) out[m * DIMC + c] = __float2bfloat16(r);
        else                             out[m * DIMC + c] = r;
    }
}

// ---------------- bf16 MFMA GEMM (BN=64): 512 thr / 8 waves, 16x32 waves -----
// R16-proven optimum for the wide-N dispatches (qkv, fc1).
#define LDP 72
template <int EPI, typename OutT>
__global__ __launch_bounds__(512) void gemm_mfma_kernel(const __hip_bfloat16* __restrict__ A,
                                                        const __hip_bfloat16* __restrict__ Wt,
                                                        const float* __restrict__ bias,
                                                        const float* __restrict__ res,
                                                        OutT* __restrict__ C,
                                                        int M, int N, int K) {
    __shared__ __hip_bfloat16 As[64][LDP];
    __shared__ __hip_bfloat16 Ws[64][LDP];
    int tid = threadIdx.x;
    int bm = blockIdx.y * 64, bn = blockIdx.x * 64;
    int lane = tid & 63, wid = tid >> 6;      // 8 waves
    int wr = wid >> 1, wc = wid & 1;          // wave: rows wr*16, cols wc*32
    int fr = lane & 15, fq = lane >> 4;
    f32x4 acc[2] = {};

    uint2 ra[2], rw[2];
    #pragma unroll
    for (int i = 0; i < 2; i++) {
        int idx = tid + i * 512;
        int r = idx >> 4, c = (idx & 15) << 2;
        ra[i] = *(const uint2*)&A[(size_t)(bm + r) * K + c];
        rw[i] = *(const uint2*)&Wt[(size_t)(bn + r) * K + c];
    }

    for (int k0 = 0; k0 < K; k0 += 64) {
        #pragma unroll
        for (int i = 0; i < 2; i++) {
            int idx = tid + i * 512;
            int r = idx >> 4, c = (idx & 15) << 2;
            *(uint2*)&As[r][c] = ra[i];
            *(uint2*)&Ws[r][c] = rw[i];
        }
        __syncthreads();
        if (k0 + 64 < K) {
            #pragma unroll
            for (int i = 0; i < 2; i++) {
                int idx = tid + i * 512;
                int r = idx >> 4, c = (idx & 15) << 2;
                ra[i] = *(const uint2*)&A[(size_t)(bm + r) * K + k0 + 64 + c];
                rw[i] = *(const uint2*)&Wt[(size_t)(bn + r) * K + k0 + 64 + c];
            }
        }
        #pragma unroll
        for (int kk = 0; kk < 2; kk++) {
            int kb = kk * 32 + fq * 8;
            bf16x8 af;
            {
                union { uint4 u; bf16x8 v; } ua;
                ua.u = *(const uint4*)&As[wr * 16 + fr][kb];
                af = ua.v;
            }
            #pragma unroll
            for (int j = 0; j < 2; j++) {
                union { uint4 u; bf16x8 v; } ub;
                ub.u = *(const uint4*)&Ws[wc * 32 + j * 16 + fr][kb];
                acc[j] = __builtin_amdgcn_mfma_f32_16x16x32_bf16(af, ub.v, acc[j], 0, 0, 0);
            }
        }
        __syncthreads();
    }
    int mbase = bm + wr * 16 + fq * 4;
    #pragma unroll
    for (int j = 0; j < 2; j++) {
        int n = bn + wc * 32 + j * 16 + fr;
        float bv = bias[n];
        #pragma unroll
        for (int r = 0; r < 4; r++) {
            int m = mbase + r;
            float v = acc[j][r] + bv;
            if (EPI == 1) v = v * 0.5f * (1.0f + erff(v * 0.70710678118654752f));
            if (EPI == 2) v += res[(size_t)m * N + n];
            if constexpr (sizeof(OutT) == 2) C[(size_t)m * N + n] = __float2bfloat16(v);
            else                             C[(size_t)m * N + n] = v;
        }
    }
}

// ---------------- bf16 MFMA GEMM (BN=32): for N=256 dispatches (proj, fc2) ---
// Grid (8,48)=384 blocks of 512 thr (8 waves, 16x16 each; 13.8 KB LDS):
// half the CUs co-host 2 INDEPENDENT blocks whose barrier domains drift ->
// block-level TLP (R17 showed intra-block waves saturate at 8).
template <int EPI, typename OutT>
__global__ __launch_bounds__(512) void gemm_mfma_n32_kernel(const __hip_bfloat16* __restrict__ A,
                                                            const __hip_bfloat16* __restrict__ Wt,
                                                            const float* __restrict__ bias,
                                                            const float* __restrict__ res,
                                                            OutT* __restrict__ C,
                                                            int M, int N, int K) {
    __shared__ __hip_bfloat16 As[64][LDP];
    __shared__ __hip_bfloat16 Ws[32][LDP];
    int tid = threadIdx.x;
    int bm = blockIdx.y * 64, bn = blockIdx.x * 32;
    int lane = tid & 63, wid = tid >> 6;      // 8 waves
    int wr = wid >> 1, wc = wid & 1;          // wave: rows wr*16, cols wc*16
    int fr = lane & 15, fq = lane >> 4;
    f32x4 acc = {};

    // staging: A 64x64 (2 uint2/thread), W 32x64 (1 uint2/thread)
    uint2 ra[2], rw;
    {
        int r0 = tid >> 4, c0 = (tid & 15) << 2;
        int r1 = (tid + 512) >> 4, c1 = ((tid + 512) & 15) << 2;
        ra[0] = *(const uint2*)&A[(size_t)(bm + r0) * K + c0];
        ra[1] = *(const uint2*)&A[(size_t)(bm + r1) * K + c1];
        if (tid < 512) rw = *(const uint2*)&Wt[(size_t)(bn + (tid >> 4)) * K + ((tid & 15) << 2)];
    }
    // W uses only rows 0..31: threads 0..511 map to 32 rows x 16 chunks
    int wrow = tid >> 4;          // 0..31 (tid < 512)
    int wcol = (tid & 15) << 2;
    bool wact = (wrow < 32);
    rw = *(const uint2*)&Wt[(size_t)(bn + (wrow & 31)) * K + wcol];

    for (int k0 = 0; k0 < K; k0 += 64) {
        {
            int r0 = tid >> 4, c0 = (tid & 15) << 2;
            int r1 = (tid + 512) >> 4, c1 = ((tid + 512) & 15) << 2;
            *(uint2*)&As[r0][c0] = ra[0];
            *(uint2*)&As[r1][c1] = ra[1];
            if (wact) *(uint2*)&Ws[wrow][wcol] = rw;
        }
        __syncthreads();
        if (k0 + 64 < K) {
            int r0 = tid >> 4, c0 = (tid & 15) << 2;
            int r1 = (tid + 512) >> 4, c1 = ((tid + 512) & 15) << 2;
            ra[0] = *(const uint2*)&A[(size_t)(bm + r0) * K + k0 + 64 + c0];
            ra[1] = *(const uint2*)&A[(size_t)(bm + r1) * K + k0 + 64 + c1];
            rw = *(const uint2*)&Wt[(size_t)(bn + (wrow & 31)) * K + k0 + 64 + wcol];
        }
        #pragma unroll
        for (int kk = 0; kk < 2; kk++) {
            int kb = kk * 32 + fq * 8;
            union { uint4 u; bf16x8 v; } ua, ub;
            ua.u = *(const uint4*)&As[wr * 16 + fr][kb];
            ub.u = *(const uint4*)&Ws[wc * 16 + fr][kb];
            acc = __builtin_amdgcn_mfma_f32_16x16x32_bf16(ua.v, ub.v, acc, 0, 0, 0);
        }
        __syncthreads();
    }
    int mbase = bm + wr * 16 + fq * 4;
    int n = bn + wc * 16 + fr;
    float bv = bias[n];
    #pragma unroll
    for (int r = 0; r < 4; r++) {
        int m = mbase + r;
        float v = acc[r] + bv;
        if (EPI == 1) v = v * 0.5f * (1.0f + erff(v * 0.70710678118654752f));
        if (EPI == 2) v += res[(size_t)m * N + n];
        if constexpr (sizeof(OutT) == 2) C[(size_t)m * N + n] = __float2bfloat16(v);
        else                             C[(size_t)m * N + n] = v;
    }
}

// ---------------- neighborhood attention, shared K/V LDS buffer --------------
// R14-exact (80B rows, fixed 16B slots, conflict-free b128; setprio on
// compute clusters).
__global__ __launch_bounds__(512, 4) void attn_kernel(const float* __restrict__ qkv,
                                                      const float* __restrict__ rpb,
                                                      const float* __restrict__ lrm,
                                                      __hip_bfloat16* __restrict__ out) {
    __shared__ __align__(16) unsigned KVd[KTAP * WW * 20];   // 66560 B
    __shared__ float rpbs[625];
    __shared__ float kers[NTAPS];

    int tid = threadIdx.x;
    int h = blockIdx.x >> 3;
    int n = blockIdx.x & 7;
    int q = tid >> 3;          // query column 0..63
    int c = tid & 7;           // tap-slice 0..7
    int shh = win_start(h, HH);
    int ph  = pb_start(h, HH);
    int sww = win_start(q, WW);
    int pwq = pb_start(q, WW);
    int mrow = h * WW + q;

    for (int i = tid; i < 625; i += 512) rpbs[i] = rpb[n * 625 + i];
    if (tid < NTAPS) {
        int ti = tid / KTAP, tj = tid - KTAP * ti;
        float dx = (float)(tj - NB), dy = (float)(ti - NB);
        kers[tid] = __expf(-(dx * dx + dy * dy) * (1.0f / 162.0f)) + lrm[tid] * 10.0f;
    }

    // ---- issue K loads (to regs) + Q loads ----
    float4 kreg[14], qv[8];
    #pragma unroll
    for (int it = 0; it < 7; ++it) {
        int tau = tid + 512 * it;
        if (tau < 3328) {                   // 832 rows x 4 sixteen-byte chunks
            int row = tau >> 2, j = tau & 3;
            int ti0 = row >> 6, col = row & 63;
            int ihr = shh + DIL * ti0;
            const float4* g = (const float4*)(qkv + (size_t)(ihr * WW + col) * 768
                                              + DIMC + n * HD + 8 * j);
            kreg[2 * it] = g[0]; kreg[2 * it + 1] = g[1];
        }
    }
    {
        const float4* qg = (const float4*)(qkv + (size_t)mrow * 768 + n * HD);
        #pragma unroll
        for (int i = 0; i < 8; ++i) qv[i] = qg[i];
    }

    // ---- cvt + write K (one b128 per thread-chunk, fixed slot j) ----
    #pragma unroll
    for (int it = 0; it < 7; ++it) {
        int tau = tid + 512 * it;
        if (tau < 3328) {
            int row = tau >> 2, j = tau & 3;
            float4 u0 = kreg[2 * it], u1 = kreg[2 * it + 1];
            uint4 w;
            w.x = __builtin_bit_cast(unsigned, pkh(u0.x, u0.y));
            w.y = __builtin_bit_cast(unsigned, pkh(u0.z, u0.w));
            w.z = __builtin_bit_cast(unsigned, pkh(u1.x, u1.y));
            w.w = __builtin_bit_cast(unsigned, pkh(u1.z, u1.w));
            *(uint4*)&KVd[row * 20 + j * 4] = w;
        }
    }
    // ---- pack Q (scaled) ----
    f16x2 qh[16];
    #pragma unroll
    for (int i = 0; i < 8; ++i) {
        qh[2 * i]     = pkh(qv[i].x * QSCALE, qv[i].y * QSCALE);
        qh[2 * i + 1] = pkh(qv[i].z * QSCALE, qv[i].w * QSCALE);
    }
    __syncthreads();   // #1: K + rpbs + kers visible

    // ---- issue V half-A loads (tau 0..1535, always in range) ----
    float4 vA[6];
    #pragma unroll
    for (int it = 0; it < 3; ++it) {
        int tau = tid + 512 * it;
        int row = tau >> 2, j = tau & 3;
        int ti0 = row >> 6, col = row & 63;
        int ihr = shh + DIL * ti0;
        const float4* g = (const float4*)(qkv + (size_t)(ihr * WW + col) * 768
                                          + 2 * DIMC + n * HD + 8 * j);
        vA[2 * it] = g[0]; vA[2 * it + 1] = g[1];
    }

    // ---- scores: taps t = c + 8k; incremental (ti,tj,row); b128 reads ----
    float p[22];
    float smax = -1e30f;
    __builtin_amdgcn_s_setprio(1);
    {
        int ti = 0, tj = c, tt = c;
        int row = sww + 3 * c;             // ti*64 + col, ti=0 initially
        #pragma unroll
        for (int k = 0; k < 22; ++k) {
            if (tt < NTAPS) {
                const unsigned* kp = KVd + row * 20;
                uint4 r0 = *(const uint4*)(kp);
                uint4 r1 = *(const uint4*)(kp + 4);
                uint4 r2 = *(const uint4*)(kp + 8);
                uint4 r3 = *(const uint4*)(kp + 12);
                f16x2 sa = {}, sb = {}, sc2 = {}, sd = {};
                sa  += qh[0]  * bch(r0.x); sb  += qh[1]  * bch(r0.y);
                sc2 += qh[2]  * bch(r0.z); sd  += qh[3]  * bch(r0.w);
                sa  += qh[4]  * bch(r1.x); sb  += qh[5]  * bch(r1.y);
                sc2 += qh[6]  * bch(r1.z); sd  += qh[7]  * bch(r1.w);
                sa  += qh[8]  * bch(r2.x); sb  += qh[9]  * bch(r2.y);
                sc2 += qh[10] * bch(r2.z); sd  += qh[11] * bch(r2.w);
                sa  += qh[12] * bch(r3.x); sb  += qh[13] * bch(r3.y);
                sc2 += qh[14] * bch(r3.z); sd  += qh[15] * bch(r3.w);
                f16x2 st = (sa + sb) + (sc2 + sd);
                float s = (float)st.x + (float)st.y;
                s += rpbs[(ph + ti) * 25 + pwq + tj];
                s *= kers[tt];
                p[k] = s;
                smax = fmaxf(smax, s);
            } else {
                p[k] = -1e30f;
            }
            tj += 8; row += 24;
            if (tj >= KTAP) { tj -= KTAP; ++ti; row += 25; }  // +64 (ti) -39 (col)
            tt += 8;
        }
    }
    __builtin_amdgcn_s_setprio(0);
    __syncthreads();   // #2: ALL K reads complete before V overwrites KVd

    // ---- write V half-A (loads were in flight across the score phase) ----
    #pragma unroll
    for (int it = 0; it < 3; ++it) {
        int tau = tid + 512 * it;
        int row = tau >> 2, j = tau & 3;
        float4 u0 = vA[2 * it], u1 = vA[2 * it + 1];
        uint4 w;
        w.x = __builtin_bit_cast(unsigned, pkh(u0.x, u0.y));
        w.y = __builtin_bit_cast(unsigned, pkh(u0.z, u0.w));
        w.z = __builtin_bit_cast(unsigned, pkh(u1.x, u1.y));
        w.w = __builtin_bit_cast(unsigned, pkh(u1.z, u1.w));
        *(uint4*)&KVd[row * 20 + j * 4] = w;
    }
    // ---- issue V half-B loads (tau 1536..3327) ----
    float4 vB[8];
    #pragma unroll
    for (int it = 3; it < 7; ++it) {
        int tau = tid + 512 * it;
        if (tau < 3328) {
            int row = tau >> 2, j = tau & 3;
            int ti0 = row >> 6, col = row & 63;
            int ihr = shh + DIL * ti0;
            const float4* g = (const float4*)(qkv + (size_t)(ihr * WW + col) * 768
                                              + 2 * DIMC + n * HD + 8 * j);
            vB[2 * (it - 3)] = g[0]; vB[2 * (it - 3) + 1] = g[1];
        }
    }

    // ---- softmax across the 8 c-lanes (register-only; hides vB latency) ----
    #pragma unroll
    for (int o = 1; o < 8; o <<= 1) smax = fmaxf(smax, __shfl_xor(smax, o));
    float ssum = 0.0f;
    #pragma unroll
    for (int k = 0; k < 22; ++k) {
        float e = __expf(p[k] - smax);
        p[k] = e;
        ssum += e;
    }
    #pragma unroll
    for (int o = 1; o < 8; o <<= 1) ssum += __shfl_xor(ssum, o);
    float inv = 1.0f / ssum;
    #pragma unroll
    for (int k = 0; k < 22; ++k) p[k] *= inv;

    // ---- write V half-B ----
    #pragma unroll
    for (int it = 3; it < 7; ++it) {
        int tau = tid + 512 * it;
        if (tau < 3328) {
            int row = tau >> 2, j = tau & 3;
            float4 u0 = vB[2 * (it - 3)], u1 = vB[2 * (it - 3) + 1];
            uint4 w;
            w.x = __builtin_bit_cast(unsigned, pkh(u0.x, u0.y));
            w.y = __builtin_bit_cast(unsigned, pkh(u0.z, u0.w));
            w.z = __builtin_bit_cast(unsigned, pkh(u1.x, u1.y));
            w.w = __builtin_bit_cast(unsigned, pkh(u1.z, u1.w));
            *(uint4*)&KVd[row * 20 + j * 4] = w;
        }
    }
    __syncthreads();   // #3: V fully written

    // ---- PV: own taps, packed-f16 accumulate over all 32 d ----
    f16x2 acc2[16] = {};
    __builtin_amdgcn_s_setprio(1);
    {
        int ti = 0, tj = c, tt = c;
        int row = sww + 3 * c;
        #pragma unroll
        for (int k = 0; k < 22; ++k) {
            if (tt < NTAPS) {
                const unsigned* vp = KVd + row * 20;
                uint4 r0 = *(const uint4*)(vp);
                uint4 r1 = *(const uint4*)(vp + 4);
                uint4 r2 = *(const uint4*)(vp + 8);
                uint4 r3 = *(const uint4*)(vp + 12);
                f16x2 p2 = pkh(p[k], p[k]);
                acc2[0]  += p2 * bch(r0.x); acc2[1]  += p2 * bch(r0.y);
                acc2[2]  += p2 * bch(r0.z); acc2[3]  += p2 * bch(r0.w);
                acc2[4]  += p2 * bch(r1.x); acc2[5]  += p2 * bch(r1.y);
                acc2[6]  += p2 * bch(r1.z); acc2[7]  += p2 * bch(r1.w);
                acc2[8]  += p2 * bch(r2.x); acc2[9]  += p2 * bch(r2.y);
                acc2[10] += p2 * bch(r2.z); acc2[11] += p2 * bch(r2.w);
                acc2[12] += p2 * bch(r3.x); acc2[13] += p2 * bch(r3.y);
                acc2[14] += p2 * bch(r3.z); acc2[15] += p2 * bch(r3.w);
            }
            tj += 8; row += 24;
            if (tj >= KTAP) { tj -= KTAP; ++ti; row += 25; }
            tt += 8;
        }
    }
    __builtin_amdgcn_s_setprio(0);
    // ---- reduce-scatter across 8 c-lanes; lane c keeps d = 4c..4c+3 ----
    f16x2 r8v[8];
    {
        bool b = (c & 4);
        #pragma unroll
        for (int i = 0; i < 8; ++i) {
            f16x2 keep = b ? acc2[i + 8] : acc2[i];
            f16x2 send = b ? acc2[i] : acc2[i + 8];
            float sf = __shfl_xor(__builtin_bit_cast(float, send), 4);
            r8v[i] = keep + __builtin_bit_cast(f16x2, sf);
        }
    }
    f16x2 r4v[4];
    {
        bool b = (c & 2);
        #pragma unroll
        for (int i = 0; i < 4; ++i) {
            f16x2 keep = b ? r8v[i + 4] : r8v[i];
            f16x2 send = b ? r8v[i] : r8v[i + 4];
            float sf = __shfl_xor(__builtin_bit_cast(float, send), 2);
            r4v[i] = keep + __builtin_bit_cast(f16x2, sf);
        }
    }
    f16x2 r2v[2];
    {
        bool b = (c & 1);
        #pragma unroll
        for (int i = 0; i < 2; ++i) {
            f16x2 keep = b ? r4v[i + 2] : r4v[i];
            f16x2 send = b ? r4v[i] : r4v[i + 2];
            float sf = __shfl_xor(__builtin_bit_cast(float, send), 1);
            r2v[i] = keep + __builtin_bit_cast(f16x2, sf);
        }
    }
    union { __hip_bfloat16 hh[4]; ushort4 u4; } ow;
    ow.hh[0] = __float2bfloat16((float)r2v[0].x);
    ow.hh[1] = __float2bfloat16((float)r2v[0].y);
    ow.hh[2] = __float2bfloat16((float)r2v[1].x);
    ow.hh[3] = __float2bfloat16((float)r2v[1].y);
    *(ushort4*)&out[(size_t)mrow * DIMC + n * HD + c * 4] = ow.u4;
}

// ---------------- launch -----------------------------------------------------
extern "C" void kernel_launch(void* const* d_in, const int* in_sizes, int n_in,
                              void* d_out, int out_size, void* d_ws, size_t ws_size,
                              hipStream_t stream) {
    const float* x      = (const float*)d_in[0];
    const float* ln1_w  = (const float*)d_in[1];
    const float* ln1_b  = (const float*)d_in[2];
    const float* qkv_w  = (const float*)d_in[3];
    const float* qkv_b  = (const float*)d_in[4];
    const float* rpb    = (const float*)d_in[5];
    const float* lr_m   = (const float*)d_in[6];
    const float* proj_w = (const float*)d_in[7];
    const float* proj_b = (const float*)d_in[8];
    const float* ln2_w  = (const float*)d_in[9];
    const float* ln2_b  = (const float*)d_in[10];
    const float* fc1_w  = (const float*)d_in[11];
    const float* fc1_b  = (const float*)d_in[12];
    const float* fc2_w  = (const float*)d_in[13];
    const float* fc2_b  = (const float*)d_in[14];
    const float* nf_w   = (const float*)d_in[15];
    const float* nf_b   = (const float*)d_in[16];
    float* out = (float*)d_out;

    char* ws = (char*)d_ws;
    float*          t        = (float*)ws;                               //  3 MB
    float*          qkvb     = (float*)(ws + 3145728);                   //  9.4 MB
    __hip_bfloat16* y        = (__hip_bfloat16*)(ws + 12582912);         //  1.5 MB
    __hip_bfloat16* attn_out = (__hip_bfloat16*)(ws + 14155776);         //  1.5 MB
    __hip_bfloat16* m1       = (__hip_bfloat16*)(ws + 15728640);         //  6 MB
    __hip_bfloat16* qkv_wb   = (__hip_bfloat16*)(ws + 22020096);         //  2.25 MB
    __hip_bfloat16* proj_wb  = (__hip_bfloat16*)(ws + 24379392);         //  0.75 MB
    __hip_bfloat16* fc1_wb   = (__hip_bfloat16*)(ws + 25165824);         //  3 MB
    __hip_bfloat16* fc2_wb   = (__hip_bfloat16*)(ws + 28311552);         //  3 MB

    // one launch converts all 4 weight buffers (1179648 float4s total)
    cvt_all_kernel<<<1179648 / 256, 256, 0, stream>>>(
        qkv_w, proj_w, fc1_w, fc2_w, qkv_wb, proj_wb, fc1_wb, fc2_wb);

    transpose_in_kernel<<<MROWS, 256, 0, stream>>>(x, t);

    for (int l = 0; l < 6; l++) {
        const __hip_bfloat16* qw  = qkv_wb  + (size_t)l * 768 * 256;
        const __hip_bfloat16* pw  = proj_wb + (size_t)l * 256 * 256;
        const __hip_bfloat16* f1w = fc1_wb  + (size_t)l * 1024 * 256;
        const __hip_bfloat16* f2w = fc2_wb  + (size_t)l * 256 * 1024;
        const float* qb  = qkv_b  + (size_t)l * 768;
        const float* pb  = proj_b + (size_t)l * 256;
        const float* f1b = fc1_b  + (size_t)l * 1024;
        const float* f2b = fc2_b  + (size_t)l * 256;
        const float* rp  = rpb    + (size_t)l * NHEADS * 25 * 25;
        const float* lm  = lr_m   + (size_t)l * NTAPS;

        ln_kernel<__hip_bfloat16, 0><<<MROWS, 256, 0, stream>>>(
            t, ln1_w + l * 256, ln1_b + l * 256, y);
        gemm_mfma_kernel<0, float><<<dim3(768 / 64, MROWS / 64), 512, 0, stream>>>(
            y, qw, qb, nullptr, qkvb, MROWS, 768, 256);
        attn_kernel<<<HH * NHEADS, 512, 0, stream>>>(qkvb, rp, lm, attn_out);
        gemm_mfma_n32_kernel<2, float><<<dim3(256 / 32, MROWS / 64), 512, 0, stream>>>(
            attn_out, pw, pb, t, t, MROWS, 256, 256);
        ln_kernel<__hip_bfloat16, 0><<<MROWS, 256, 0, stream>>>(
            t, ln2_w + l * 256, ln2_b + l * 256, y);
        gemm_mfma_kernel<1, __hip_bfloat16><<<dim3(1024 / 64, MROWS / 64), 512, 0, stream>>>(
            y, f1w, f1b, nullptr, m1, MROWS, 1024, 256);
        gemm_mfma_n32_kernel<2, float><<<dim3(256 / 32, MROWS / 64), 512, 0, stream>>>(
            m1, f2w, f2b, t, t, MROWS, 256, 1024);
    }

    ln_kernel<float, 1><<<MROWS, 256, 0, stream>>>(t, nf_w, nf_b, out);
}

// Round 21
// 368.093 us; speedup vs baseline: 1.0994x; 1.0154x over previous
//
#include <hip/hip_runtime.h>
#include <hip/hip_bf16.h>
#include <math.h>

// Problem constants (compile-time)
#define DIMC   256
#define HH     48
#define WW     64
#define MROWS  (HH*WW)     // 3072
#define NHEADS 8
#define HD     32
#define KTAP   13
#define NTAPS  (KTAP*KTAP) // 169
#define DIL    3
#define NB     6           // KTAP/2
#define EPSLN  1e-5f
#define QSCALE 0.17677669529663687f  // 32^-0.5

typedef __attribute__((ext_vector_type(8))) short bf16x8;
typedef __attribute__((ext_vector_type(4))) float f32x4;
typedef _Float16 __f16;
typedef __f16 f16x2 __attribute__((ext_vector_type(2)));

__device__ __forceinline__ f16x2 pkh(float a, float b) {
    auto r = __builtin_amdgcn_cvt_pkrtz(a, b);
    return __builtin_bit_cast(f16x2, r);
}
__device__ __forceinline__ f16x2 bch(unsigned u) {
    return __builtin_bit_cast(f16x2, u);
}

// ---------------- window/bias start helpers (static arithmetic) -------------
__device__ __forceinline__ int win_start(int i, int L) {
    int imodd = i % DIL;
    if (i - NB * DIL < 0) return imodd;
    if (i + NB * DIL >= L) {
        int a = (L / DIL) * DIL;
        int b = L - a;
        if (imodd < b) return L - b + imodd - 2 * NB * DIL;
        return a + imodd - KTAP * DIL;
    }
    return i - NB * DIL;
}
__device__ __forceinline__ int pb_start(int i, int L) {
    if (i - NB * DIL < 0) return KTAP - 1 - i / DIL;
    if (i + NB * DIL >= L) return (L - 1 - i) / DIL;
    return NB;
}

// ---------------- fp32 -> bf16 conversion, all 4 weight buffers in 1 launch --
__global__ __launch_bounds__(256) void cvt_all_kernel(const float* __restrict__ w0,
                                                      const float* __restrict__ w1,
                                                      const float* __restrict__ w2,
                                                      const float* __restrict__ w3,
                                                      __hip_bfloat16* __restrict__ o0,
                                                      __hip_bfloat16* __restrict__ o1,
                                                      __hip_bfloat16* __restrict__ o2,
                                                      __hip_bfloat16* __restrict__ o3) {
    int i = blockIdx.x * 256 + threadIdx.x;
    const float* in;
    __hip_bfloat16* out;
    int off;
    if (i < 294912)      { in = w0; out = o0; off = i; }
    else if (i < 393216) { in = w1; out = o1; off = i - 294912; }
    else if (i < 786432) { in = w2; out = o2; off = i - 393216; }
    else                 { in = w3; out = o3; off = i - 786432; }
    float4 v = ((const float4*)in)[off];
    union { __hip_bfloat16 h[4]; ushort4 u; } p;
    p.h[0] = __float2bfloat16(v.x);
    p.h[1] = __float2bfloat16(v.y);
    p.h[2] = __float2bfloat16(v.z);
    p.h[3] = __float2bfloat16(v.w);
    ((ushort4*)out)[off] = p.u;
}

// ---------------- input transpose: x (C, H*W) -> t (H*W, C) -----------------
__global__ void transpose_in_kernel(const float* __restrict__ x, float* __restrict__ t) {
    int m = blockIdx.x;
    int c = threadIdx.x;
    t[m * DIMC + c] = x[c * MROWS + m];
}

// ---------------- layernorm; OutT float or bf16; optional transposed store ---
template <typename OutT, int TRANS>
__global__ __launch_bounds__(256) void ln_kernel(const float* __restrict__ in,
                                                 const float* __restrict__ w,
                                                 const float* __restrict__ b,
                                                 OutT* __restrict__ out) {
    __shared__ float s1[4], s2[4];
    int m = blockIdx.x;
    int c = threadIdx.x;
    float v = in[m * DIMC + c];
    float a = v, q = v * v;
    #pragma unroll
    for (int o = 32; o > 0; o >>= 1) {
        a += __shfl_xor(a, o);
        q += __shfl_xor(q, o);
    }
    if ((threadIdx.x & 63) == 0) { s1[threadIdx.x >> 6] = a; s2[threadIdx.x >> 6] = q; }
    __syncthreads();
    float mean = (s1[0] + s1[1] + s1[2] + s1[3]) * (1.0f / DIMC);
    float var  = (s2[0] + s2[1] + s2[2] + s2[3]) * (1.0f / DIMC) - mean * mean;
    float r = (v - mean) * rsqrtf(var + EPSLN) * w[c] + b[c];
    if (TRANS) {
        out[c * MROWS + m] = (OutT)r;
    } else {
        if constexpr (sizeof(OutT) == 2) out[m * DIMC + c] = __float2bfloat16(r);
        else                             out[m * DIMC + c] = r;
    }
}

// ---------------- bf16 MFMA GEMM (BN=64): 512 thr / 8 waves, 16x32 waves -----
// R16-proven optimum for the wide-N dispatches (qkv, fc1).
#define LDP 72
template <int EPI, typename OutT>
__global__ __launch_bounds__(512) void gemm_mfma_kernel(const __hip_bfloat16* __restrict__ A,
                                                        const __hip_bfloat16* __restrict__ Wt,
                                                        const float* __restrict__ bias,
                                                        const float* __restrict__ res,
                                                        OutT* __restrict__ C,
                                                        int M, int N, int K) {
    __shared__ __hip_bfloat16 As[64][LDP];
    __shared__ __hip_bfloat16 Ws[64][LDP];
    int tid = threadIdx.x;
    int bm = blockIdx.y * 64, bn = blockIdx.x * 64;
    int lane = tid & 63, wid = tid >> 6;      // 8 waves
    int wr = wid >> 1, wc = wid & 1;          // wave: rows wr*16, cols wc*32
    int fr = lane & 15, fq = lane >> 4;
    f32x4 acc[2] = {};

    uint2 ra[2], rw[2];
    #pragma unroll
    for (int i = 0; i < 2; i++) {
        int idx = tid + i * 512;
        int r = idx >> 4, c = (idx & 15) << 2;
        ra[i] = *(const uint2*)&A[(size_t)(bm + r) * K + c];
        rw[i] = *(const uint2*)&Wt[(size_t)(bn + r) * K + c];
    }

    for (int k0 = 0; k0 < K; k0 += 64) {
        #pragma unroll
        for (int i = 0; i < 2; i++) {
            int idx = tid + i * 512;
            int r = idx >> 4, c = (idx & 15) << 2;
            *(uint2*)&As[r][c] = ra[i];
            *(uint2*)&Ws[r][c] = rw[i];
        }
        __syncthreads();
        if (k0 + 64 < K) {
            #pragma unroll
            for (int i = 0; i < 2; i++) {
                int idx = tid + i * 512;
                int r = idx >> 4, c = (idx & 15) << 2;
                ra[i] = *(const uint2*)&A[(size_t)(bm + r) * K + k0 + 64 + c];
                rw[i] = *(const uint2*)&Wt[(size_t)(bn + r) * K + k0 + 64 + c];
            }
        }
        #pragma unroll
        for (int kk = 0; kk < 2; kk++) {
            int kb = kk * 32 + fq * 8;
            bf16x8 af;
            {
                union { uint4 u; bf16x8 v; } ua;
                ua.u = *(const uint4*)&As[wr * 16 + fr][kb];
                af = ua.v;
            }
            #pragma unroll
            for (int j = 0; j < 2; j++) {
                union { uint4 u; bf16x8 v; } ub;
                ub.u = *(const uint4*)&Ws[wc * 32 + j * 16 + fr][kb];
                acc[j] = __builtin_amdgcn_mfma_f32_16x16x32_bf16(af, ub.v, acc[j], 0, 0, 0);
            }
        }
        __syncthreads();
    }
    int mbase = bm + wr * 16 + fq * 4;
    #pragma unroll
    for (int j = 0; j < 2; j++) {
        int n = bn + wc * 32 + j * 16 + fr;
        float bv = bias[n];
        #pragma unroll
        for (int r = 0; r < 4; r++) {
            int m = mbase + r;
            float v = acc[j][r] + bv;
            if (EPI == 1) v = v * 0.5f * (1.0f + erff(v * 0.70710678118654752f));
            if (EPI == 2) v += res[(size_t)m * N + n];
            if constexpr (sizeof(OutT) == 2) C[(size_t)m * N + n] = __float2bfloat16(v);
            else                             C[(size_t)m * N + n] = v;
        }
    }
}

// ---------------- bf16 MFMA GEMM (32x32 tile): N=256 dispatches (proj, fc2) --
// 256 thr / 4 waves (16x16 each), 9.2 KB LDS. Grid (8,96)=768 blocks ->
// EXACTLY 3 blocks/CU (balanced; R19's 384-block grid left half the CUs
// with 1 block while the other half's 2 blocks set the duration).
template <int EPI, typename OutT>
__global__ __launch_bounds__(256) void gemm_mfma_t32_kernel(const __hip_bfloat16* __restrict__ A,
                                                            const __hip_bfloat16* __restrict__ Wt,
                                                            const float* __restrict__ bias,
                                                            const float* __restrict__ res,
                                                            OutT* __restrict__ C,
                                                            int M, int N, int K) {
    __shared__ __hip_bfloat16 As[32][LDP];
    __shared__ __hip_bfloat16 Ws[32][LDP];
    int tid = threadIdx.x;
    int bm = blockIdx.y * 32, bn = blockIdx.x * 32;
    int lane = tid & 63, wid = tid >> 6;      // 4 waves
    int wr = wid >> 1, wc = wid & 1;          // wave: rows wr*16, cols wc*16
    int fr = lane & 15, fq = lane >> 4;
    f32x4 acc = {};

    // staging: A 32x64 (2048 elems), W 32x64 -> 2 uint2/thread each
    uint2 ra[2], rw[2];
    #pragma unroll
    for (int i = 0; i < 2; i++) {
        int idx = tid + i * 256;
        int r = idx >> 4, c = (idx & 15) << 2;
        ra[i] = *(const uint2*)&A[(size_t)(bm + r) * K + c];
        rw[i] = *(const uint2*)&Wt[(size_t)(bn + r) * K + c];
    }

    for (int k0 = 0; k0 < K; k0 += 64) {
        #pragma unroll
        for (int i = 0; i < 2; i++) {
            int idx = tid + i * 256;
            int r = idx >> 4, c = (idx & 15) << 2;
            *(uint2*)&As[r][c] = ra[i];
            *(uint2*)&Ws[r][c] = rw[i];
        }
        __syncthreads();
        if (k0 + 64 < K) {
            #pragma unroll
            for (int i = 0; i < 2; i++) {
                int idx = tid + i * 256;
                int r = idx >> 4, c = (idx & 15) << 2;
                ra[i] = *(const uint2*)&A[(size_t)(bm + r) * K + k0 + 64 + c];
                rw[i] = *(const uint2*)&Wt[(size_t)(bn + r) * K + k0 + 64 + c];
            }
        }
        #pragma unroll
        for (int kk = 0; kk < 2; kk++) {
            int kb = kk * 32 + fq * 8;
            union { uint4 u; bf16x8 v; } ua, ub;
            ua.u = *(const uint4*)&As[wr * 16 + fr][kb];
            ub.u = *(const uint4*)&Ws[wc * 16 + fr][kb];
            acc = __builtin_amdgcn_mfma_f32_16x16x32_bf16(ua.v, ub.v, acc, 0, 0, 0);
        }
        __syncthreads();
    }
    int mbase = bm + wr * 16 + fq * 4;
    int n = bn + wc * 16 + fr;
    float bv = bias[n];
    #pragma unroll
    for (int r = 0; r < 4; r++) {
        int m = mbase + r;
        float v = acc[r] + bv;
        if (EPI == 1) v = v * 0.5f * (1.0f + erff(v * 0.70710678118654752f));
        if (EPI == 2) v += res[(size_t)m * N + n];
        if constexpr (sizeof(OutT) == 2) C[(size_t)m * N + n] = __float2bfloat16(v);
        else                             C[(size_t)m * N + n] = v;
    }
}

// ---------------- neighborhood attention, shared K/V LDS buffer --------------
// R14-exact (80B rows, fixed 16B slots, conflict-free b128; setprio on
// compute clusters).
__global__ __launch_bounds__(512, 4) void attn_kernel(const float* __restrict__ qkv,
                                                      const float* __restrict__ rpb,
                                                      const float* __restrict__ lrm,
                                                      __hip_bfloat16* __restrict__ out) {
    __shared__ __align__(16) unsigned KVd[KTAP * WW * 20];   // 66560 B
    __shared__ float rpbs[625];
    __shared__ float kers[NTAPS];

    int tid = threadIdx.x;
    int h = blockIdx.x >> 3;
    int n = blockIdx.x & 7;
    int q = tid >> 3;          // query column 0..63
    int c = tid & 7;           // tap-slice 0..7
    int shh = win_start(h, HH);
    int ph  = pb_start(h, HH);
    int sww = win_start(q, WW);
    int pwq = pb_start(q, WW);
    int mrow = h * WW + q;

    for (int i = tid; i < 625; i += 512) rpbs[i] = rpb[n * 625 + i];
    if (tid < NTAPS) {
        int ti = tid / KTAP, tj = tid - KTAP * ti;
        float dx = (float)(tj - NB), dy = (float)(ti - NB);
        kers[tid] = __expf(-(dx * dx + dy * dy) * (1.0f / 162.0f)) + lrm[tid] * 10.0f;
    }

    // ---- issue K loads (to regs) + Q loads ----
    float4 kreg[14], qv[8];
    #pragma unroll
    for (int it = 0; it < 7; ++it) {
        int tau = tid + 512 * it;
        if (tau < 3328) {                   // 832 rows x 4 sixteen-byte chunks
            int row = tau >> 2, j = tau & 3;
            int ti0 = row >> 6, col = row & 63;
            int ihr = shh + DIL * ti0;
            const float4* g = (const float4*)(qkv + (size_t)(ihr * WW + col) * 768
                                              + DIMC + n * HD + 8 * j);
            kreg[2 * it] = g[0]; kreg[2 * it + 1] = g[1];
        }
    }
    {
        const float4* qg = (const float4*)(qkv + (size_t)mrow * 768 + n * HD);
        #pragma unroll
        for (int i = 0; i < 8; ++i) qv[i] = qg[i];
    }

    // ---- cvt + write K (one b128 per thread-chunk, fixed slot j) ----
    #pragma unroll
    for (int it = 0; it < 7; ++it) {
        int tau = tid + 512 * it;
        if (tau < 3328) {
            int row = tau >> 2, j = tau & 3;
            float4 u0 = kreg[2 * it], u1 = kreg[2 * it + 1];
            uint4 w;
            w.x = __builtin_bit_cast(unsigned, pkh(u0.x, u0.y));
            w.y = __builtin_bit_cast(unsigned, pkh(u0.z, u0.w));
            w.z = __builtin_bit_cast(unsigned, pkh(u1.x, u1.y));
            w.w = __builtin_bit_cast(unsigned, pkh(u1.z, u1.w));
            *(uint4*)&KVd[row * 20 + j * 4] = w;
        }
    }
    // ---- pack Q (scaled) ----
    f16x2 qh[16];
    #pragma unroll
    for (int i = 0; i < 8; ++i) {
        qh[2 * i]     = pkh(qv[i].x * QSCALE, qv[i].y * QSCALE);
        qh[2 * i + 1] = pkh(qv[i].z * QSCALE, qv[i].w * QSCALE);
    }
    __syncthreads();   // #1: K + rpbs + kers visible

    // ---- issue V half-A loads (tau 0..1535, always in range) ----
    float4 vA[6];
    #pragma unroll
    for (int it = 0; it < 3; ++it) {
        int tau = tid + 512 * it;
        int row = tau >> 2, j = tau & 3;
        int ti0 = row >> 6, col = row & 63;
        int ihr = shh + DIL * ti0;
        const float4* g = (const float4*)(qkv + (size_t)(ihr * WW + col) * 768
                                          + 2 * DIMC + n * HD + 8 * j);
        vA[2 * it] = g[0]; vA[2 * it + 1] = g[1];
    }

    // ---- scores: taps t = c + 8k; incremental (ti,tj,row); b128 reads ----
    float p[22];
    float smax = -1e30f;
    __builtin_amdgcn_s_setprio(1);
    {
        int ti = 0, tj = c, tt = c;
        int row = sww + 3 * c;             // ti*64 + col, ti=0 initially
        #pragma unroll
        for (int k = 0; k < 22; ++k) {
            if (tt < NTAPS) {
                const unsigned* kp = KVd + row * 20;
                uint4 r0 = *(const uint4*)(kp);
                uint4 r1 = *(const uint4*)(kp + 4);
                uint4 r2 = *(const uint4*)(kp + 8);
                uint4 r3 = *(const uint4*)(kp + 12);
                f16x2 sa = {}, sb = {}, sc2 = {}, sd = {};
                sa  += qh[0]  * bch(r0.x); sb  += qh[1]  * bch(r0.y);
                sc2 += qh[2]  * bch(r0.z); sd  += qh[3]  * bch(r0.w);
                sa  += qh[4]  * bch(r1.x); sb  += qh[5]  * bch(r1.y);
                sc2 += qh[6]  * bch(r1.z); sd  += qh[7]  * bch(r1.w);
                sa  += qh[8]  * bch(r2.x); sb  += qh[9]  * bch(r2.y);
                sc2 += qh[10] * bch(r2.z); sd  += qh[11] * bch(r2.w);
                sa  += qh[12] * bch(r3.x); sb  += qh[13] * bch(r3.y);
                sc2 += qh[14] * bch(r3.z); sd  += qh[15] * bch(r3.w);
                f16x2 st = (sa + sb) + (sc2 + sd);
                float s = (float)st.x + (float)st.y;
                s += rpbs[(ph + ti) * 25 + pwq + tj];
                s *= kers[tt];
                p[k] = s;
                smax = fmaxf(smax, s);
            } else {
                p[k] = -1e30f;
            }
            tj += 8; row += 24;
            if (tj >= KTAP) { tj -= KTAP; ++ti; row += 25; }  // +64 (ti) -39 (col)
            tt += 8;
        }
    }
    __builtin_amdgcn_s_setprio(0);
    __syncthreads();   // #2: ALL K reads complete before V overwrites KVd

    // ---- write V half-A (loads were in flight across the score phase) ----
    #pragma unroll
    for (int it = 0; it < 3; ++it) {
        int tau = tid + 512 * it;
        int row = tau >> 2, j = tau & 3;
        float4 u0 = vA[2 * it], u1 = vA[2 * it + 1];
        uint4 w;
        w.x = __builtin_bit_cast(unsigned, pkh(u0.x, u0.y));
        w.y = __builtin_bit_cast(unsigned, pkh(u0.z, u0.w));
        w.z = __builtin_bit_cast(unsigned, pkh(u1.x, u1.y));
        w.w = __builtin_bit_cast(unsigned, pkh(u1.z, u1.w));
        *(uint4*)&KVd[row * 20 + j * 4] = w;
    }
    // ---- issue V half-B loads (tau 1536..3327) ----
    float4 vB[8];
    #pragma unroll
    for (int it = 3; it < 7; ++it) {
        int tau = tid + 512 * it;
        if (tau < 3328) {
            int row = tau >> 2, j = tau & 3;
            int ti0 = row >> 6, col = row & 63;
            int ihr = shh + DIL * ti0;
            const float4* g = (const float4*)(qkv + (size_t)(ihr * WW + col) * 768
                                              + 2 * DIMC + n * HD + 8 * j);
            vB[2 * (it - 3)] = g[0]; vB[2 * (it - 3) + 1] = g[1];
        }
    }

    // ---- softmax across the 8 c-lanes (register-only; hides vB latency) ----
    #pragma unroll
    for (int o = 1; o < 8; o <<= 1) smax = fmaxf(smax, __shfl_xor(smax, o));
    float ssum = 0.0f;
    #pragma unroll
    for (int k = 0; k < 22; ++k) {
        float e = __expf(p[k] - smax);
        p[k] = e;
        ssum += e;
    }
    #pragma unroll
    for (int o = 1; o < 8; o <<= 1) ssum += __shfl_xor(ssum, o);
    float inv = 1.0f / ssum;
    #pragma unroll
    for (int k = 0; k < 22; ++k) p[k] *= inv;

    // ---- write V half-B ----
    #pragma unroll
    for (int it = 3; it < 7; ++it) {
        int tau = tid + 512 * it;
        if (tau < 3328) {
            int row = tau >> 2, j = tau & 3;
            float4 u0 = vB[2 * (it - 3)], u1 = vB[2 * (it - 3) + 1];
            uint4 w;
            w.x = __builtin_bit_cast(unsigned, pkh(u0.x, u0.y));
            w.y = __builtin_bit_cast(unsigned, pkh(u0.z, u0.w));
            w.z = __builtin_bit_cast(unsigned, pkh(u1.x, u1.y));
            w.w = __builtin_bit_cast(unsigned, pkh(u1.z, u1.w));
            *(uint4*)&KVd[row * 20 + j * 4] = w;
        }
    }
    __syncthreads();   // #3: V fully written

    // ---- PV: own taps, packed-f16 accumulate over all 32 d ----
    f16x2 acc2[16] = {};
    __builtin_amdgcn_s_setprio(1);
    {
        int ti = 0, tj = c, tt = c;
        int row = sww + 3 * c;
        #pragma unroll
        for (int k = 0; k < 22; ++k) {
            if (tt < NTAPS) {
                const unsigned* vp = KVd + row * 20;
                uint4 r0 = *(const uint4*)(vp);
                uint4 r1 = *(const uint4*)(vp + 4);
                uint4 r2 = *(const uint4*)(vp + 8);
                uint4 r3 = *(const uint4*)(vp + 12);
                f16x2 p2 = pkh(p[k], p[k]);
                acc2[0]  += p2 * bch(r0.x); acc2[1]  += p2 * bch(r0.y);
                acc2[2]  += p2 * bch(r0.z); acc2[3]  += p2 * bch(r0.w);
                acc2[4]  += p2 * bch(r1.x); acc2[5]  += p2 * bch(r1.y);
                acc2[6]  += p2 * bch(r1.z); acc2[7]  += p2 * bch(r1.w);
                acc2[8]  += p2 * bch(r2.x); acc2[9]  += p2 * bch(r2.y);
                acc2[10] += p2 * bch(r2.z); acc2[11] += p2 * bch(r2.w);
                acc2[12] += p2 * bch(r3.x); acc2[13] += p2 * bch(r3.y);
                acc2[14] += p2 * bch(r3.z); acc2[15] += p2 * bch(r3.w);
            }
            tj += 8; row += 24;
            if (tj >= KTAP) { tj -= KTAP; ++ti; row += 25; }
            tt += 8;
        }
    }
    __builtin_amdgcn_s_setprio(0);
    // ---- reduce-scatter across 8 c-lanes; lane c keeps d = 4c..4c+3 ----
    f16x2 r8v[8];
    {
        bool b = (c & 4);
        #pragma unroll
        for (int i = 0; i < 8; ++i) {
            f16x2 keep = b ? acc2[i + 8] : acc2[i];
            f16x2 send = b ? acc2[i] : acc2[i + 8];
            float sf = __shfl_xor(__builtin_bit_cast(float, send), 4);
            r8v[i] = keep + __builtin_bit_cast(f16x2, sf);
        }
    }
    f16x2 r4v[4];
    {
        bool b = (c & 2);
        #pragma unroll
        for (int i = 0; i < 4; ++i) {
            f16x2 keep = b ? r8v[i + 4] : r8v[i];
            f16x2 send = b ? r8v[i] : r8v[i + 4];
            float sf = __shfl_xor(__builtin_bit_cast(float, send), 2);
            r4v[i] = keep + __builtin_bit_cast(f16x2, sf);
        }
    }
    f16x2 r2v[2];
    {
        bool b = (c & 1);
        #pragma unroll
        for (int i = 0; i < 2; ++i) {
            f16x2 keep = b ? r4v[i + 2] : r4v[i];
            f16x2 send = b ? r4v[i] : r4v[i + 2];
            float sf = __shfl_xor(__builtin_bit_cast(float, send), 1);
            r2v[i] = keep + __builtin_bit_cast(f16x2, sf);
        }
    }
    union { __hip_bfloat16 hh[4]; ushort4 u4; } ow;
    ow.hh[0] = __float2bfloat16((float)r2v[0].x);
    ow.hh[1] = __float2bfloat16((float)r2v[0].y);
    ow.hh[2] = __float2bfloat16((float)r2v[1].x);
    ow.hh[3] = __float2bfloat16((float)r2v[1].y);
    *(ushort4*)&out[(size_t)mrow * DIMC + n * HD + c * 4] = ow.u4;
}

// ---------------- launch -----------------------------------------------------
extern "C" void kernel_launch(void* const* d_in, const int* in_sizes, int n_in,
                              void* d_out, int out_size, void* d_ws, size_t ws_size,
                              hipStream_t stream) {
    const float* x      = (const float*)d_in[0];
    const float* ln1_w  = (const float*)d_in[1];
    const float* ln1_b  = (const float*)d_in[2];
    const float* qkv_w  = (const float*)d_in[3];
    const float* qkv_b  = (const float*)d_in[4];
    const float* rpb    = (const float*)d_in[5];
    const float* lr_m   = (const float*)d_in[6];
    const float* proj_w = (const float*)d_in[7];
    const float* proj_b = (const float*)d_in[8];
    const float* ln2_w  = (const float*)d_in[9];
    const float* ln2_b  = (const float*)d_in[10];
    const float* fc1_w  = (const float*)d_in[11];
    const float* fc1_b  = (const float*)d_in[12];
    const float* fc2_w  = (const float*)d_in[13];
    const float* fc2_b  = (const float*)d_in[14];
    const float* nf_w   = (const float*)d_in[15];
    const float* nf_b   = (const float*)d_in[16];
    float* out = (float*)d_out;

    char* ws = (char*)d_ws;
    float*          t        = (float*)ws;                               //  3 MB
    float*          qkvb     = (float*)(ws + 3145728);                   //  9.4 MB
    __hip_bfloat16* y        = (__hip_bfloat16*)(ws + 12582912);         //  1.5 MB
    __hip_bfloat16* attn_out = (__hip_bfloat16*)(ws + 14155776);         //  1.5 MB
    __hip_bfloat16* m1       = (__hip_bfloat16*)(ws + 15728640);         //  6 MB
    __hip_bfloat16* qkv_wb   = (__hip_bfloat16*)(ws + 22020096);         //  2.25 MB
    __hip_bfloat16* proj_wb  = (__hip_bfloat16*)(ws + 24379392);         //  0.75 MB
    __hip_bfloat16* fc1_wb   = (__hip_bfloat16*)(ws + 25165824);         //  3 MB
    __hip_bfloat16* fc2_wb   = (__hip_bfloat16*)(ws + 28311552);         //  3 MB

    // one launch converts all 4 weight buffers (1179648 float4s total)
    cvt_all_kernel<<<1179648 / 256, 256, 0, stream>>>(
        qkv_w, proj_w, fc1_w, fc2_w, qkv_wb, proj_wb, fc1_wb, fc2_wb);

    transpose_in_kernel<<<MROWS, 256, 0, stream>>>(x, t);

    for (int l = 0; l < 6; l++) {
        const __hip_bfloat16* qw  = qkv_wb  + (size_t)l * 768 * 256;
        const __hip_bfloat16* pw  = proj_wb + (size_t)l * 256 * 256;
        const __hip_bfloat16* f1w = fc1_wb  + (size_t)l * 1024 * 256;
        const __hip_bfloat16* f2w = fc2_wb  + (size_t)l * 256 * 1024;
        const float* qb  = qkv_b  + (size_t)l * 768;
        const float* pb  = proj_b + (size_t)l * 256;
        const float* f1b = fc1_b  + (size_t)l * 1024;
        const float* f2b = fc2_b  + (size_t)l * 256;
        const float* rp  = rpb    + (size_t)l * NHEADS * 25 * 25;
        const float* lm  = lr_m   + (size_t)l * NTAPS;

        ln_kernel<__hip_bfloat16, 0><<<MROWS, 256, 0, stream>>>(
            t, ln1_w + l * 256, ln1_b + l * 256, y);
        gemm_mfma_kernel<0, float><<<dim3(768 / 64, MROWS / 64), 512, 0, stream>>>(
            y, qw, qb, nullptr, qkvb, MROWS, 768, 256);
        attn_kernel<<<HH * NHEADS, 512, 0, stream>>>(qkvb, rp, lm, attn_out);
        gemm_mfma_t32_kernel<2, float><<<dim3(256 / 32, MROWS / 32), 256, 0, stream>>>(
            attn_out, pw, pb, t, t, MROWS, 256, 256);
        ln_kernel<__hip_bfloat16, 0><<<MROWS, 256, 0, stream>>>(
            t, ln2_w + l * 256, ln2_b + l * 256, y);
        gemm_mfma_kernel<1, __hip_bfloat16><<<dim3(1024 / 64, MROWS / 64), 512, 0, stream>>>(
            y, f1w, f1b, nullptr, m1, MROWS, 1024, 256);
        gemm_mfma_t32_kernel<2, float><<<dim3(256 / 32, MROWS / 32), 256, 0, stream>>>(
            m1, f2w, f2b, t, t, MROWS, 256, 1024);
    }

    ln_kernel<float, 1><<<MROWS, 256, 0, stream>>>(t, nf_w, nf_b, out);
}